// Round 2
// 907.005 us; speedup vs baseline: 1.0655x; 1.0655x over previous
//
#include <hip/hip_runtime.h>
#include <cstdint>
#include <cstddef>

// ---------------------------------------------------------------------------
// FullyDynamicSTGNN: GAT(128 nodes, T=64, B=32) -> 2-layer Transformer(d=2048)
// -> linear head.  Heavy GEMMs in bf16 MFMA (16x16x32), everything else fp32.
// R5 == R4 resubmit (round-1 bench died infra-side: no pytest/mismatch output).
// R4: GEMMs rebuilt as 1-deep double-buffered pipelines (stage(next) issued
//     before MFMA, ONE __syncthreads per K-step = the T3 minimum 2-phase
//     recipe; the implicit vmcnt(0) drain now overlaps the MFMA phase).
//     LDS XOR-swizzle applied the rule-21-correct way (linear gload_lds dest,
//     pre-swizzled GLOBAL source col, swizzled ds_read col).
//     gemm_bt:  BK=32 dbuf (32KB LDS -> 768 QKV blocks all co-resident, 3/CU)
//     gemm_bt64:BK=64 dbuf (48KB LDS, 512 blocks = 2/CU)
//     attn: f32x4 QK^T inner loop (pad 132), bf16x8 staging, 4-lane softmax.
//     ln: f32x4 loads/stores.  GAT unchanged (VALU-floor-bound, next round).
// ---------------------------------------------------------------------------

typedef unsigned short u16;
typedef __bf16 bf16x8 __attribute__((ext_vector_type(8)));
typedef float f32x4 __attribute__((ext_vector_type(4)));
typedef unsigned int u32x4 __attribute__((ext_vector_type(4)));
typedef float f32x4v __attribute__((ext_vector_type(4)));
typedef unsigned short u16x4 __attribute__((ext_vector_type(4)));

__device__ __forceinline__ u16 f2b(float f) {
  union { float f; unsigned u; } x; x.f = f;
  unsigned r = x.u + 0x7fffu + ((x.u >> 16) & 1u);   // RNE
  return (u16)(r >> 16);
}
__device__ __forceinline__ float b2f(u16 s) {
  union { unsigned u; float f; } x; x.u = ((unsigned)s) << 16;
  return x.f;
}
__device__ __forceinline__ float b2f_lo(unsigned q) {
  union { unsigned u; float f; } x; x.u = q << 16;
  return x.f;
}
__device__ __forceinline__ float b2f_hi(unsigned q) {
  union { unsigned u; float f; } x; x.u = q & 0xffff0000u;
  return x.f;
}

// async global->LDS, 16B per lane; lds dest must be wave-uniform base (+lane*16)
__device__ __forceinline__ void gload_lds16(const void* g, void* l) {
  __builtin_amdgcn_global_load_lds(
      (const __attribute__((address_space(1))) unsigned int*)g,
      (__attribute__((address_space(3))) unsigned int*)l, 16, 0, 0);
}

// ---------------------------------------------------------------------------
// GAT kernel: one 1024-thread block per (b,t) graph.  (unchanged from R3)
// ---------------------------------------------------------------------------
__global__ __launch_bounds__(1024) void gat_kernel(
    const float* __restrict__ X, const float* __restrict__ V_Adap,
    const int* __restrict__ class_idx,
    const float* __restrict__ Wl, const float* __restrict__ bl,
    const float* __restrict__ Wr, const float* __restrict__ br,
    const float* __restrict__ att, const float* __restrict__ gat_bias,
    const float* __restrict__ Wfc, const float* __restrict__ bfc,
    float* __restrict__ h_f32, u16* __restrict__ h_b16)
{
  const int bt = blockIdx.x;
  const int tid = threadIdx.x;

  __shared__ __align__(16) float xlT[64 * 132];     // 33792
  __shared__ __align__(16) float xrT[64 * 132];     // 33792
  __shared__ __align__(16) u16   xlTb[64 * 136];    // 17408
  __shared__ __align__(16) u16   esbT[128 * 136];   // 34816
  __shared__ __align__(16) u16   aggb[128 * 72];    // 18432
  __shared__ __align__(16) float WlT[64 * 20];      // 5120  [h][f]
  __shared__ __align__(16) float WrT[64 * 20];      // 5120
  __shared__ __align__(16) float WfcT[16 * 66];     // 4224  [s][h]
  __shared__ float atts[64], bls[64], brs[64], gbias[64], bfcs[16];
  __shared__ float cls[128], crs[128], inv_s[128];
  __shared__ float red[8 * 128];                    // 4096

  // --- stage 0: load weights ---
  {
    const int h = tid >> 4, f = tid & 15;
    WlT[h * 20 + f] = Wl[f * 64 + h];
    WrT[h * 20 + f] = Wr[f * 64 + h];
    WfcT[f * 66 + h] = Wfc[h * 16 + f];    // f plays 's' here
  }
  if (tid < 64) { atts[tid] = att[tid]; bls[tid] = bl[tid]; brs[tid] = br[tid]; gbias[tid] = gat_bias[tid]; }
  if (tid < 16) bfcs[tid] = bfc[tid];
  const int cidx = *class_idx;
  __syncthreads();

  // --- stage 1: xl = x@Wl+bl, xr = x@Wr+br (node n = tid>>3, h strided) ---
  {
    const int n = tid >> 3, hq = tid & 7;
    const float* xp = X + (size_t)bt * 2048 + n * 16;
    float xv[16];
    #pragma unroll
    for (int f4 = 0; f4 < 4; f4++) {
      f32x4v t4 = ((const f32x4v*)xp)[f4];
      xv[f4 * 4 + 0] = t4[0]; xv[f4 * 4 + 1] = t4[1];
      xv[f4 * 4 + 2] = t4[2]; xv[f4 * 4 + 3] = t4[3];
    }
    #pragma unroll
    for (int k = 0; k < 8; k++) {
      const int h = hq + 8 * k;
      float al = bls[h], ar = brs[h];
      #pragma unroll
      for (int f4 = 0; f4 < 4; f4++) {
        f32x4v wl = *(const f32x4v*)&WlT[h * 20 + f4 * 4];
        f32x4v wr = *(const f32x4v*)&WrT[h * 20 + f4 * 4];
        #pragma unroll
        for (int f = 0; f < 4; f++) {
          al = fmaf(xv[f4 * 4 + f], wl[f], al);
          ar = fmaf(xv[f4 * 4 + f], wr[f], ar);
        }
      }
      xlT[h * 132 + n] = al;
      xrT[h * 132 + n] = ar;
      xlTb[h * 136 + n] = f2b(al);
    }
  }
  __syncthreads();

  // --- stage 2: cl[n] = att.xl[n], cr[n] = att.xr[n] ---
  if (tid < 256) {
    const int n = tid & 127;
    const float* srcT = (tid < 128) ? xlT : xrT;
    float s = 0.f;
    for (int h = 0; h < 64; h++) s = fmaf(atts[h], srcT[h * 132 + n], s);
    if (tid < 128) cls[n] = s; else crs[n] = s;
  }
  __syncthreads();

  // --- stage 3: e[i][j], written TRANSPOSED to esbT[j][i] (bf16 x4 packed) ---
  {
    const int i0 = (tid >> 5) * 4;        // 0..124 step 4
    const int j0 = (tid & 31) * 4;        // 0..124 step 4
    float acc[4][4] = {};                 // [a=i][b=j]
    #pragma unroll 2
    for (int h = 0; h < 64; h++) {
      const float ah = atts[h];
      f32x4v xa = *(const f32x4v*)&xlT[h * 132 + i0];
      f32x4v xb = *(const f32x4v*)&xrT[h * 132 + j0];
      #pragma unroll
      for (int a = 0; a < 4; a++)
        #pragma unroll
        for (int b = 0; b < 4; b++)
          acc[a][b] = fmaf(ah, __builtin_fabsf(xa[a] + xb[b]), acc[a][b]);
    }
    const float* Vc = V_Adap + (size_t)cidx * 16384;
    float vm[4][4];
    #pragma unroll
    for (int a = 0; a < 4; a++) {
      f32x4v vc = *(const f32x4v*)&Vc[(size_t)(i0 + a) * 128 + j0];
      #pragma unroll
      for (int b = 0; b < 4; b++) vm[a][b] = vc[b];
    }
    #pragma unroll
    for (int b = 0; b < 4; b++) {
      const int j = j0 + b;
      const float ej = 0.6f * crs[j];
      u16x4 pk;
      #pragma unroll
      for (int a = 0; a < 4; a++) {
        const int i = i0 + a;
        const float e = ej + 0.6f * cls[i] + 0.4f * acc[a][b];
        // sigmoid(v)/128 > 0.004  <=>  v > ln(0.512/0.488)
        const bool m = (vm[a][b] > 0.04800922f) || (i == j);
        pk[a] = f2b(m ? e : -1e9f);
      }
      *(u16x4*)&esbT[j * 136 + i0] = pk;
    }
  }
  __syncthreads();

  // --- stage 4: p = exp(e) in-place on esbT rows; row-sum -> inv_s ---
  {
    const int j = tid >> 3, c = tid & 7;
    u16* rp = &esbT[j * 136 + c * 16];
    float ps = 0.f;
    #pragma unroll
    for (int half = 0; half < 2; half++) {
      u32x4 q = *(u32x4*)(rp + half * 8);
      #pragma unroll
      for (int w2 = 0; w2 < 4; w2++) {
        const float p0 = __expf(b2f_lo(q[w2]));
        const float p1 = __expf(b2f_hi(q[w2]));
        ps += p0 + p1;
        q[w2] = (unsigned)f2b(p0) | ((unsigned)f2b(p1) << 16);
      }
      *(u32x4*)(rp + half * 8) = q;
    }
    red[c * 128 + j] = ps;
  }
  __syncthreads();
  if (tid < 128) {
    float s = 0.f;
    #pragma unroll
    for (int c = 0; c < 8; c++) s += red[c * 128 + tid];
    inv_s[tid] = 1.f / s;
  }
  __syncthreads();

  // --- stage 5: agg[j][h] = (1/s_j) sum_i p^T[j][i] xl[i][h]  via MFMA ---
  {
    const int w = tid >> 6, lane = tid & 63;
    const int lq = lane >> 4, lr = lane & 15;
    const int jt = w >> 1, ht0 = (w & 1) * 2;
    f32x4 acc2[2] = {};
    #pragma unroll
    for (int ks = 0; ks < 4; ks++) {
      const bf16x8 af = __builtin_bit_cast(bf16x8,
          *(const u32x4*)&esbT[(jt * 16 + lr) * 136 + ks * 32 + lq * 8]);
      #pragma unroll
      for (int t = 0; t < 2; t++) {
        const bf16x8 bfb = __builtin_bit_cast(bf16x8,
            *(const u32x4*)&xlTb[((ht0 + t) * 16 + lr) * 136 + ks * 32 + lq * 8]);
        acc2[t] = __builtin_amdgcn_mfma_f32_16x16x32_bf16(af, bfb, acc2[t], 0, 0, 0);
      }
    }
    #pragma unroll
    for (int t = 0; t < 2; t++) {
      const int h = (ht0 + t) * 16 + lr;
      const float gb = gbias[h];
      #pragma unroll
      for (int r = 0; r < 4; r++) {
        const int j = jt * 16 + lq * 4 + r;
        aggb[j * 72 + h] = f2b(acc2[t][r] * inv_s[j] + gb);
      }
    }
  }
  __syncthreads();

  // --- stage 6: out = agg @ Wfc + bfc -> h (fp32 + bf16) ---
  {
    const int j = tid >> 3, s0 = (tid & 7) * 2;
    float o0 = bfcs[s0], o1 = bfcs[s0 + 1];
    #pragma unroll
    for (int h8 = 0; h8 < 8; h8++) {
      u32x4 q = *(const u32x4*)&aggb[j * 72 + h8 * 8];
      #pragma unroll
      for (int w2 = 0; w2 < 4; w2++) {
        const int h = h8 * 8 + w2 * 2;
        const float a0 = b2f_lo(q[w2]);
        const float a1 = b2f_hi(q[w2]);
        o0 = fmaf(a0, WfcT[s0 * 66 + h], o0);
        o1 = fmaf(a0, WfcT[(s0 + 1) * 66 + h], o1);
        o0 = fmaf(a1, WfcT[s0 * 66 + h + 1], o0);
        o1 = fmaf(a1, WfcT[(s0 + 1) * 66 + h + 1], o1);
      }
    }
    const size_t off = (size_t)bt * 2048 + j * 16 + s0;
    h_f32[off] = o0; h_f32[off + 1] = o1;
    h_b16[off] = f2b(o0); h_b16[off + 1] = f2b(o1);
  }
}

// ---------------------------------------------------------------------------
// transpose + cast: src (2048 x 2048) fp32 row-major -> dst bf16 (dst[n][k] =
// src[k][n]).  Up to 3 matrices via blockIdx.z.
// ---------------------------------------------------------------------------
struct TransArgs {
  const float* s0; const float* s1; const float* s2;
  u16* d0; u16* d1; u16* d2;
};

__global__ __launch_bounds__(256) void transpose_cast(TransArgs p)
{
  const float* src = (blockIdx.z == 0) ? p.s0 : (blockIdx.z == 1) ? p.s1 : p.s2;
  u16* dst = (blockIdx.z == 0) ? p.d0 : (blockIdx.z == 1) ? p.d1 : p.d2;
  __shared__ u16 tile[64][66];
  const int k0 = blockIdx.y * 64, n0 = blockIdx.x * 64;
  const int tid = threadIdx.x;
  const int c = tid & 63, rb = tid >> 6;
  #pragma unroll
  for (int r = 0; r < 16; r++) {
    const int k = rb + r * 4;
    tile[k][c] = f2b(src[(size_t)(k0 + k) * 2048 + n0 + c]);
  }
  __syncthreads();
  #pragma unroll
  for (int r = 0; r < 16; r++) {
    const int n = rb + r * 4;
    dst[(size_t)(n0 + n) * 2048 + k0 + c] = tile[c][n];
  }
}

// ---------------------------------------------------------------------------
// bf16 MFMA GEMM: C[m][n] = sum_k A[m][k] * Bt[n][k] + bias[n]
// 1-deep double-buffered pipeline.  Per K-step:
//   stage(next buf) ; ds_read+MFMA(cur buf) ; __syncthreads (drains vmcnt
//   AFTER the MFMA phase -> prefetch latency hidden) ; swap.
// LDS XOR-swizzle: gload_lds writes linearly, so the swizzle is applied by
// permuting the per-lane GLOBAL source column (involution) and XORing the
// ds_read column with the same pattern.  Kills the stride-conflict on
// ds_read_b128 at zero instruction cost.
// MODE 0: fp32 out ; 1: bf16 out ; 2: bf16 + relu
// ---------------------------------------------------------------------------
struct GemmArgs {
  const u16* A;
  const u16* Bt0; const u16* Bt1; const u16* Bt2;
  const float* b0; const float* b1; const float* b2;
  void* C0; void* C1; void* C2;
  int N; int K;
};

// 128x128 tile, BK=32, dbuf (32KB LDS -> all 768 QKV blocks co-resident).
template <int MODE>
__global__ __launch_bounds__(256) void gemm_bt(GemmArgs g)
{
  const int z = blockIdx.z;
  const u16* Bt = (z == 0) ? g.Bt0 : (z == 1) ? g.Bt1 : g.Bt2;
  const float* bias = (z == 0) ? g.b0 : (z == 1) ? g.b1 : g.b2;
  void* C = (z == 0) ? g.C0 : (z == 1) ? g.C1 : g.C2;
  const int N = g.N, K = g.K;
  const int m0 = blockIdx.y * 128, n0 = blockIdx.x * 128;

  __shared__ __align__(16) u16 As[2][128 * 32];   // 16KB
  __shared__ __align__(16) u16 Bs[2][128 * 32];   // 16KB

  const int tid = threadIdx.x;
  const int lane = tid & 63, w = tid >> 6;
  // staging: per call a wave covers 16 rows x 32 cols (64B/row).
  // swizzled source col: lane with lds col (lane&3)*8, row-low (lane>>2)&3
  // must fetch global col ((lane&3) ^ ((lane>>2)&3))*8.
  const int srow = w * 16 + (lane >> 2);
  const int scol = ((lane & 3) ^ ((lane >> 2) & 3)) * 8;
  const u16* gA = g.A + (size_t)(m0 + srow) * K + scol;
  const u16* gB = Bt + (size_t)(n0 + srow) * K + scol;
  const int lbase = (w * 16) * 32;

  const int wm = (w >> 1) * 64, wn = (w & 1) * 64;
  const int lq = lane >> 4, lr = lane & 15;
  const int csw = (lr & 3) << 3;                  // read-side XOR (elements)

  f32x4 acc[4][4] = {};
  const int NT = K >> 5;

  auto stage = [&](int buf, int kt) {
    const int kk = kt << 5;
    #pragma unroll
    for (int c = 0; c < 2; c++) {
      gload_lds16(gA + (size_t)(c * 64) * K + kk, &As[buf][lbase + c * 64 * 32]);
      gload_lds16(gB + (size_t)(c * 64) * K + kk, &Bs[buf][lbase + c * 64 * 32]);
    }
  };
  auto compute = [&](int buf) {
    bf16x8 af[4], bfr[4];
    #pragma unroll
    for (int i = 0; i < 4; i++) {
      af[i] = __builtin_bit_cast(bf16x8,
          *(const u32x4*)&As[buf][(wm + i * 16 + lr) * 32 + ((lq * 8) ^ csw)]);
      bfr[i] = __builtin_bit_cast(bf16x8,
          *(const u32x4*)&Bs[buf][(wn + i * 16 + lr) * 32 + ((lq * 8) ^ csw)]);
    }
    #pragma unroll
    for (int mi = 0; mi < 4; mi++)
      #pragma unroll
      for (int ni = 0; ni < 4; ni++)
        acc[mi][ni] = __builtin_amdgcn_mfma_f32_16x16x32_bf16(af[mi], bfr[ni], acc[mi][ni], 0, 0, 0);
  };

  stage(0, 0);
  __syncthreads();
  int cur = 0;
  for (int kt = 0; kt + 1 < NT; ++kt) {
    stage(cur ^ 1, kt + 1);       // prefetch next K-tile (async, in flight)
    compute(cur);                 // MFMA on current tile hides the latency
    __syncthreads();              // vmcnt(0)+barrier: next tile ready, cur free
    cur ^= 1;
  }
  compute(cur);                   // last tile, no prefetch

  #pragma unroll
  for (int ni = 0; ni < 4; ni++) {
    const int col = n0 + wn + ni * 16 + lr;
    const float bv = bias[col];
    #pragma unroll
    for (int mi = 0; mi < 4; mi++) {
      #pragma unroll
      for (int r = 0; r < 4; r++) {
        const int row = m0 + wm + mi * 16 + lq * 4 + r;
        float v = acc[mi][ni][r] + bv;
        if (MODE == 0) {
          ((float*)C)[(size_t)row * N + col] = v;
        } else {
          if (MODE == 2) v = fmaxf(v, 0.f);
          ((u16*)C)[(size_t)row * N + col] = f2b(v);
        }
      }
    }
  }
}

// 128(M) x 64(N) tile, BK=64, dbuf (48KB LDS): grid (N/64, M/128) = 512 blocks
// -> 2 blocks/CU co-resident.
template <int MODE>
__global__ __launch_bounds__(256) void gemm_bt64(GemmArgs g)
{
  const u16* Bt = g.Bt0;
  const float* bias = g.b0;
  void* C = g.C0;
  const int N = g.N, K = g.K;
  const int m0 = blockIdx.y * 128, n0 = blockIdx.x * 64;

  __shared__ __align__(16) u16 As[2][128 * 64];   // 32KB
  __shared__ __align__(16) u16 Bs[2][64 * 64];    // 16KB

  const int tid = threadIdx.x;
  const int lane = tid & 63, w = tid >> 6;
  // staging: per call a wave covers 8 rows x 64 cols (128B/row).
  const int srow = w * 8 + (lane >> 3);
  const int scol = ((lane & 7) ^ (lane >> 3)) * 8;   // pre-swizzled global col
  const u16* gA = g.A + (size_t)(m0 + srow) * K + scol;
  const u16* gB = Bt + (size_t)(n0 + srow) * K + scol;
  const int lbase = (w * 8) * 64;

  const int wm = w * 32;
  const int lq = lane >> 4, lr = lane & 15;
  const int csw = (lr & 7) << 3;                  // read-side XOR (elements)

  f32x4 acc[2][4] = {};
  const int NT = K >> 6;

  auto stage = [&](int buf, int kt) {
    const int kk = kt << 6;
    #pragma unroll
    for (int c = 0; c < 4; c++)
      gload_lds16(gA + (size_t)(c * 32) * K + kk, &As[buf][lbase + c * 32 * 64]);
    #pragma unroll
    for (int c = 0; c < 2; c++)
      gload_lds16(gB + (size_t)(c * 32) * K + kk, &Bs[buf][lbase + c * 32 * 64]);
  };
  auto compute = [&](int buf) {
    #pragma unroll
    for (int ks = 0; ks < 2; ks++) {
      bf16x8 af[2], bfr[4];
      #pragma unroll
      for (int i = 0; i < 2; i++)
        af[i] = __builtin_bit_cast(bf16x8,
            *(const u32x4*)&As[buf][(wm + i * 16 + lr) * 64 + ((ks * 32 + lq * 8) ^ csw)]);
      #pragma unroll
      for (int i = 0; i < 4; i++)
        bfr[i] = __builtin_bit_cast(bf16x8,
            *(const u32x4*)&Bs[buf][(i * 16 + lr) * 64 + ((ks * 32 + lq * 8) ^ csw)]);
      #pragma unroll
      for (int mi = 0; mi < 2; mi++)
        #pragma unroll
        for (int ni = 0; ni < 4; ni++)
          acc[mi][ni] = __builtin_amdgcn_mfma_f32_16x16x32_bf16(af[mi], bfr[ni], acc[mi][ni], 0, 0, 0);
    }
  };

  stage(0, 0);
  __syncthreads();
  int cur = 0;
  for (int kt = 0; kt + 1 < NT; ++kt) {
    stage(cur ^ 1, kt + 1);
    compute(cur);
    __syncthreads();
    cur ^= 1;
  }
  compute(cur);

  #pragma unroll
  for (int ni = 0; ni < 4; ni++) {
    const int col = n0 + ni * 16 + lr;
    const float bv = bias[col];
    #pragma unroll
    for (int mi = 0; mi < 2; mi++) {
      #pragma unroll
      for (int r = 0; r < 4; r++) {
        const int row = m0 + wm + mi * 16 + lq * 4 + r;
        float v = acc[mi][ni][r] + bv;
        if (MODE == 0) {
          ((float*)C)[(size_t)row * N + col] = v;
        } else {
          if (MODE == 2) v = fmaxf(v, 0.f);
          ((u16*)C)[(size_t)row * N + col] = f2b(v);
        }
      }
    }
  }
}

// ---------------------------------------------------------------------------
// attention: one block per (head, batch).  S=64, DH=128, fp32 softmax in LDS.
// bf16x8 staging loads, f32x4 QK^T inner loop (row pad 132 for 16B alignment;
// K rows strided by 16 across lanes), softmax 4 lanes/row.
// ---------------------------------------------------------------------------
__global__ __launch_bounds__(256) void attn_kernel(
    const u16* __restrict__ Qb, const u16* __restrict__ Kb,
    const u16* __restrict__ Vb, u16* __restrict__ AOb)
{
  const int head = blockIdx.x, b = blockIdx.y;
  const int tid = threadIdx.x;
  __shared__ __align__(16) float qs[64 * 132];
  __shared__ __align__(16) float ks[64 * 132];
  __shared__ __align__(16) float vs[64 * 128];
  __shared__ __align__(16) float ss[64 * 65];
  const size_t base = ((size_t)b * 64) * 2048 + (size_t)head * 128;

  for (int idx = tid; idx < 1024; idx += 256) {
    const int t_ = idx >> 4, d8 = (idx & 15) * 8;
    const size_t gp = base + (size_t)t_ * 2048 + d8;
    const u32x4 q = *(const u32x4*)(Qb + gp);
    const u32x4 k = *(const u32x4*)(Kb + gp);
    const u32x4 v = *(const u32x4*)(Vb + gp);
    f32x4 q0 = {b2f_lo(q[0]), b2f_hi(q[0]), b2f_lo(q[1]), b2f_hi(q[1])};
    f32x4 q1 = {b2f_lo(q[2]), b2f_hi(q[2]), b2f_lo(q[3]), b2f_hi(q[3])};
    f32x4 k0 = {b2f_lo(k[0]), b2f_hi(k[0]), b2f_lo(k[1]), b2f_hi(k[1])};
    f32x4 k1 = {b2f_lo(k[2]), b2f_hi(k[2]), b2f_lo(k[3]), b2f_hi(k[3])};
    f32x4 v0 = {b2f_lo(v[0]), b2f_hi(v[0]), b2f_lo(v[1]), b2f_hi(v[1])};
    f32x4 v1 = {b2f_lo(v[2]), b2f_hi(v[2]), b2f_lo(v[3]), b2f_hi(v[3])};
    *(f32x4*)&qs[t_ * 132 + d8] = q0; *(f32x4*)&qs[t_ * 132 + d8 + 4] = q1;
    *(f32x4*)&ks[t_ * 132 + d8] = k0; *(f32x4*)&ks[t_ * 132 + d8 + 4] = k1;
    *(f32x4*)&vs[t_ * 128 + d8] = v0; *(f32x4*)&vs[t_ * 128 + d8 + 4] = v1;
  }
  __syncthreads();

  {
    const int i0 = (tid >> 4) * 4, j0 = tid & 15;
    float acc[4][4] = {};
    #pragma unroll 2
    for (int d0 = 0; d0 < 128; d0 += 4) {
      f32x4 qv[4], kv[4];
      #pragma unroll
      for (int a = 0; a < 4; a++) qv[a] = *(const f32x4*)&qs[(i0 + a) * 132 + d0];
      #pragma unroll
      for (int c = 0; c < 4; c++) kv[c] = *(const f32x4*)&ks[(j0 + c * 16) * 132 + d0];
      #pragma unroll
      for (int a = 0; a < 4; a++)
        #pragma unroll
        for (int c = 0; c < 4; c++)
          #pragma unroll
          for (int e = 0; e < 4; e++)
            acc[a][c] = fmaf(qv[a][e], kv[c][e], acc[a][c]);
    }
    const float sc = 0.08838834764831845f;  // 1/sqrt(128)
    #pragma unroll
    for (int a = 0; a < 4; a++)
      #pragma unroll
      for (int c = 0; c < 4; c++)
        ss[(i0 + a) * 65 + j0 + c * 16] = acc[a][c] * sc;
  }
  __syncthreads();

  {
    const int row = tid >> 2;
    float* rp = &ss[row * 65 + (tid & 3) * 16];
    float mx = -3e38f;
    #pragma unroll
    for (int j = 0; j < 16; j++) mx = fmaxf(mx, rp[j]);
    mx = fmaxf(mx, __shfl_xor(mx, 1, 64));
    mx = fmaxf(mx, __shfl_xor(mx, 2, 64));
    float s = 0.f;
    #pragma unroll
    for (int j = 0; j < 16; j++) { const float p = __expf(rp[j] - mx); rp[j] = p; s += p; }
    s += __shfl_xor(s, 1, 64);
    s += __shfl_xor(s, 2, 64);
    const float inv = 1.f / s;
    #pragma unroll
    for (int j = 0; j < 16; j++) rp[j] *= inv;
  }
  __syncthreads();

  {
    const int i0 = (tid >> 4) * 4, d0 = (tid & 15) * 8;
    float o[4][8] = {};
    for (int j = 0; j < 64; j++) {
      float pv[4];
      #pragma unroll
      for (int a = 0; a < 4; a++) pv[a] = ss[(i0 + a) * 65 + j];
      f32x4v v0 = *(const f32x4v*)&vs[j * 128 + d0];
      f32x4v v1 = *(const f32x4v*)&vs[j * 128 + d0 + 4];
      float vv[8] = {v0[0], v0[1], v0[2], v0[3], v1[0], v1[1], v1[2], v1[3]};
      #pragma unroll
      for (int a = 0; a < 4; a++)
        #pragma unroll
        for (int c = 0; c < 8; c++)
          o[a][c] = fmaf(pv[a], vv[c], o[a][c]);
    }
    #pragma unroll
    for (int a = 0; a < 4; a++)
      #pragma unroll
      for (int c = 0; c < 8; c++)
        AOb[base + (size_t)(i0 + a) * 2048 + d0 + c] = f2b(o[a][c]);
  }
}

// ---------------------------------------------------------------------------
// fused residual + layernorm: h = LN(hin + delta) ; writes fp32 + bf16
// f32x4 loads/stores, u16x4 bf16 stores.
// ---------------------------------------------------------------------------
__global__ __launch_bounds__(256) void ln_kernel(
    const float* __restrict__ hin, const float* __restrict__ delta,
    const float* __restrict__ gamma, const float* __restrict__ beta,
    float* __restrict__ hout, u16* __restrict__ bout_)
{
  const int token = blockIdx.x, tid = threadIdx.x;
  const size_t off = (size_t)token * 2048;
  __shared__ float red[8];
  f32x4 v[2];
  float s = 0.f;
  #pragma unroll
  for (int r = 0; r < 2; r++) {
    const int i = r * 1024 + tid * 4;
    const f32x4 a = *(const f32x4*)(hin + off + i);
    const f32x4 b = *(const f32x4*)(delta + off + i);
    v[r] = a + b;
    s += v[r][0] + v[r][1] + v[r][2] + v[r][3];
  }
  #pragma unroll
  for (int o = 32; o > 0; o >>= 1) s += __shfl_down(s, o, 64);
  if ((tid & 63) == 0) red[tid >> 6] = s;
  __syncthreads();
  const float mean = (red[0] + red[1] + red[2] + red[3]) * (1.f / 2048.f);
  float s2 = 0.f;
  #pragma unroll
  for (int r = 0; r < 2; r++)
    #pragma unroll
    for (int e = 0; e < 4; e++) { const float d = v[r][e] - mean; s2 = fmaf(d, d, s2); }
  #pragma unroll
  for (int o = 32; o > 0; o >>= 1) s2 += __shfl_down(s2, o, 64);
  if ((tid & 63) == 0) red[4 + (tid >> 6)] = s2;
  __syncthreads();
  const float var = (red[4] + red[5] + red[6] + red[7]) * (1.f / 2048.f);
  const float rstd = rsqrtf(var + 1e-5f);
  #pragma unroll
  for (int r = 0; r < 2; r++) {
    const int i = r * 1024 + tid * 4;
    const f32x4 gm = *(const f32x4*)(gamma + i);
    const f32x4 bt = *(const f32x4*)(beta + i);
    f32x4 y;
    u16x4 pb;
    #pragma unroll
    for (int e = 0; e < 4; e++) {
      y[e] = (v[r][e] - mean) * rstd * gm[e] + bt[e];
      pb[e] = f2b(y[e]);
    }
    *(f32x4*)(hout + off + i) = y;
    *(u16x4*)(bout_ + off + i) = pb;
  }
}

// ---------------------------------------------------------------------------
// head: out[b][o] = h[b, T-1, :] . Wout[:, o] + bout[o]
// ---------------------------------------------------------------------------
__global__ __launch_bounds__(256) void final_kernel(
    const float* __restrict__ h, const float* __restrict__ Wout,
    const float* __restrict__ bout, float* __restrict__ out)
{
  const int b = blockIdx.x, tid = threadIdx.x;
  __shared__ float row[2048];
  __shared__ float part[256];
  const float* hr = h + ((size_t)b * 64 + 63) * 2048;
  for (int i = tid; i < 2048; i += 256) row[i] = hr[i];
  __syncthreads();
  const int o = tid & 15, ch = tid >> 4;
  float s = 0.f;
  if (o < 10) {
    const int i0 = ch * 128;
    for (int i = i0; i < i0 + 128; i++) s = fmaf(row[i], Wout[(size_t)i * 10 + o], s);
  }
  part[tid] = s;
  __syncthreads();
  if (tid < 10) {
    float t = bout[tid];
    for (int c2 = 0; c2 < 16; c2++) t += part[c2 * 16 + tid];
    out[(size_t)b * 10 + tid] = t;
  }
}

// ---------------------------------------------------------------------------
extern "C" void kernel_launch(void* const* d_in, const int* in_sizes, int n_in,
                              void* d_out, int out_size, void* d_ws, size_t ws_size,
                              hipStream_t stream)
{
  const float* X        = (const float*)d_in[0];
  const float* V_Adap   = (const float*)d_in[1];
  const float* Wl       = (const float*)d_in[2];
  const float* bl       = (const float*)d_in[3];
  const float* Wr       = (const float*)d_in[4];
  const float* br       = (const float*)d_in[5];
  const float* att      = (const float*)d_in[6];
  const float* gat_bias = (const float*)d_in[7];
  const float* Wfc      = (const float*)d_in[8];
  const float* bfc      = (const float*)d_in[9];
  const float* Wq       = (const float*)d_in[10];
  const float* bq       = (const float*)d_in[11];
  const float* Wk       = (const float*)d_in[12];
  const float* bk       = (const float*)d_in[13];
  const float* Wv       = (const float*)d_in[14];
  const float* bv       = (const float*)d_in[15];
  const float* Wo       = (const float*)d_in[16];
  const float* bo       = (const float*)d_in[17];
  const float* ln1_g    = (const float*)d_in[18];
  const float* ln1_b    = (const float*)d_in[19];
  const float* W1       = (const float*)d_in[20];
  const float* b1       = (const float*)d_in[21];
  const float* W2       = (const float*)d_in[22];
  const float* b2       = (const float*)d_in[23];
  const float* ln2_g    = (const float*)d_in[24];
  const float* ln2_b    = (const float*)d_in[25];
  const float* WoutP    = (const float*)d_in[26];
  const float* boutP    = (const float*)d_in[27];
  const int*   class_idx = (const int*)d_in[28];

  char* ws = (char*)d_ws;
  const size_t MB = (size_t)1 << 20;
  float* h_f32 = (float*)(ws);               // 16 MB  (B*T, D) fp32
  u16*   h_b16 = (u16*)(ws + 16 * MB);       //  8 MB
  u16*   Qb    = (u16*)(ws + 24 * MB);       //  8 MB
  u16*   Kb    = (u16*)(ws + 32 * MB);       //  8 MB
  u16*   Vb    = (u16*)(ws + 40 * MB);       //  8 MB
  u16*   AOb   = (u16*)(ws + 48 * MB);       //  8 MB
  float* tmp   = (float*)(ws + 56 * MB);     // 16 MB  (proj / ff2) fp32
  u16*   ff1b  = (u16*)(ws + 72 * MB);       //  8 MB
  u16*   Wt0   = (u16*)(ws + 80 * MB);       //  8 MB transposed bf16 weights
  u16*   Wt1   = (u16*)(ws + 88 * MB);       //  8 MB
  u16*   Wt2   = (u16*)(ws + 96 * MB);       //  8 MB   (total 104 MB)

  // 1. GAT over all (b,t) graphs -> h (fp32 + bf16)
  gat_kernel<<<2048, 1024, 0, stream>>>(X, V_Adap, class_idx, Wl, bl, Wr, br,
                                        att, gat_bias, Wfc, bfc, h_f32, h_b16);

  const size_t DD = 2048ull * 2048ull;
  for (int l = 0; l < 2; l++) {
    const size_t wofs = (size_t)l * DD;
    const size_t bofs = (size_t)l * 2048;

    // QKV (batched z=3, 768 blocks, all co-resident at 32KB LDS)
    transpose_cast<<<dim3(32, 32, 3), 256, 0, stream>>>(
        TransArgs{Wq + wofs, Wk + wofs, Wv + wofs, Wt0, Wt1, Wt2});
    gemm_bt<1><<<dim3(16, 16, 3), 256, 0, stream>>>(
        GemmArgs{h_b16, Wt0, Wt1, Wt2, bq + bofs, bk + bofs, bv + bofs,
                 Qb, Kb, Vb, 2048, 2048});

    attn_kernel<<<dim3(16, 32), 256, 0, stream>>>(Qb, Kb, Vb, AOb);

    // o / W1 / W2 transposed together (Wt0..2 free once QKV gemm is done)
    transpose_cast<<<dim3(32, 32, 3), 256, 0, stream>>>(
        TransArgs{Wo + wofs, W1 + wofs, W2 + wofs, Wt0, Wt1, Wt2});

    // out-proj (128x64 tiles, 512 blocks)
    gemm_bt64<0><<<dim3(32, 16), 256, 0, stream>>>(
        GemmArgs{AOb, Wt0, nullptr, nullptr, bo + bofs, nullptr, nullptr,
                 tmp, nullptr, nullptr, 2048, 2048});
    ln_kernel<<<2048, 256, 0, stream>>>(h_f32, tmp, ln1_g + bofs, ln1_b + bofs,
                                        h_f32, h_b16);

    // FF1 (relu, bf16 out)
    gemm_bt64<2><<<dim3(32, 16), 256, 0, stream>>>(
        GemmArgs{h_b16, Wt1, nullptr, nullptr, b1 + bofs, nullptr, nullptr,
                 ff1b, nullptr, nullptr, 2048, 2048});

    // FF2
    gemm_bt64<0><<<dim3(32, 16), 256, 0, stream>>>(
        GemmArgs{ff1b, Wt2, nullptr, nullptr, b2 + bofs, nullptr, nullptr,
                 tmp, nullptr, nullptr, 2048, 2048});
    ln_kernel<<<2048, 256, 0, stream>>>(h_f32, tmp, ln2_g + bofs, ln2_b + bofs,
                                        h_f32, h_b16);
  }

  final_kernel<<<32, 256, 0, stream>>>(h_f32, WoutP, boutP, (float*)d_out);
}

// Round 3
// 890.999 us; speedup vs baseline: 1.0847x; 1.0180x over previous
//
#include <hip/hip_runtime.h>
#include <cstdint>
#include <cstddef>

// ---------------------------------------------------------------------------
// FullyDynamicSTGNN: GAT(128 nodes, T=64, B=32) -> 2-layer Transformer(d=2048)
// -> linear head.  Heavy GEMMs in bf16 MFMA (16x16x32), everything else fp32.
// R6: GAT rebuilt around the LDS pipe (it was LDS-throughput-bound, not VALU):
//   stage 3: 8x2 tile, wave-uniform i0 -> A-reads are LDS broadcasts; B is one
//            b64; att[h] from global (SGPR).  LDS cy/h-iter ~23 -> ~14.
//   stage 1: (h=lane, node-group=wave) mapping; weights in registers (8 b128
//            once vs 64 per thread); X staged in LDS scratch (aggb reuse) so
//            x-reads are broadcasts; b128 output writes.
//   stage 2: 1024-thread partials + tree combine (was 256 threads x 64 iters).
// GEMM/attn/ln/transpose byte-identical to R5 (isolate the GAT delta).
// ---------------------------------------------------------------------------

typedef unsigned short u16;
typedef __bf16 bf16x8 __attribute__((ext_vector_type(8)));
typedef float f32x4 __attribute__((ext_vector_type(4)));
typedef float f32x2 __attribute__((ext_vector_type(2)));
typedef unsigned int u32x4 __attribute__((ext_vector_type(4)));
typedef float f32x4v __attribute__((ext_vector_type(4)));
typedef unsigned short u16x4 __attribute__((ext_vector_type(4)));

__device__ __forceinline__ u16 f2b(float f) {
  union { float f; unsigned u; } x; x.f = f;
  unsigned r = x.u + 0x7fffu + ((x.u >> 16) & 1u);   // RNE
  return (u16)(r >> 16);
}
__device__ __forceinline__ float b2f(u16 s) {
  union { unsigned u; float f; } x; x.u = ((unsigned)s) << 16;
  return x.f;
}
__device__ __forceinline__ float b2f_lo(unsigned q) {
  union { unsigned u; float f; } x; x.u = q << 16;
  return x.f;
}
__device__ __forceinline__ float b2f_hi(unsigned q) {
  union { unsigned u; float f; } x; x.u = q & 0xffff0000u;
  return x.f;
}

// async global->LDS, 16B per lane; lds dest must be wave-uniform base (+lane*16)
__device__ __forceinline__ void gload_lds16(const void* g, void* l) {
  __builtin_amdgcn_global_load_lds(
      (const __attribute__((address_space(1))) unsigned int*)g,
      (__attribute__((address_space(3))) unsigned int*)l, 16, 0, 0);
}

// ---------------------------------------------------------------------------
// GAT kernel: one 1024-thread block per (b,t) graph.
// ---------------------------------------------------------------------------
__global__ __launch_bounds__(1024) void gat_kernel(
    const float* __restrict__ X, const float* __restrict__ V_Adap,
    const int* __restrict__ class_idx,
    const float* __restrict__ Wl, const float* __restrict__ bl,
    const float* __restrict__ Wr, const float* __restrict__ br,
    const float* __restrict__ att, const float* __restrict__ gat_bias,
    const float* __restrict__ Wfc, const float* __restrict__ bfc,
    float* __restrict__ h_f32, u16* __restrict__ h_b16)
{
  const int bt = blockIdx.x;
  const int tid = threadIdx.x;

  __shared__ __align__(16) float xlT[64 * 132];     // 33792
  __shared__ __align__(16) float xrT[64 * 132];     // 33792
  __shared__ __align__(16) u16   xlTb[64 * 136];    // 17408
  __shared__ __align__(16) u16   esbT[128 * 136];   // 34816
  __shared__ __align__(16) u16   aggb[128 * 72];    // 18432 (also X scratch)
  __shared__ __align__(16) float WlT[64 * 20];      // 5120  [h][f]
  __shared__ __align__(16) float WrT[64 * 20];      // 5120
  __shared__ __align__(16) float WfcT[16 * 66];     // 4224  [s][h]
  __shared__ float atts[64], bls[64], brs[64], gbias[64], bfcs[16];
  __shared__ float cls[128], crs[128], inv_s[128];
  __shared__ float red[8 * 128];                    // 4096

  float* scratchX = (float*)aggb;   // 8KB of 18KB; aggb unused until stage 5

  // --- stage 0: load weights + stage X row-block into LDS ---
  {
    const int h = tid >> 4, f = tid & 15;
    WlT[h * 20 + f] = Wl[f * 64 + h];
    WrT[h * 20 + f] = Wr[f * 64 + h];
    WfcT[f * 66 + h] = Wfc[h * 16 + f];    // f plays 's' here
  }
  if (tid < 64) { atts[tid] = att[tid]; bls[tid] = bl[tid]; brs[tid] = br[tid]; gbias[tid] = gat_bias[tid]; }
  if (tid < 16) bfcs[tid] = bfc[tid];
  if (tid < 512)
    ((f32x4*)scratchX)[tid] = ((const f32x4*)(X + (size_t)bt * 2048))[tid];
  const int cidx = *class_idx;
  __syncthreads();

  // --- stage 1: xl = x@Wl+bl, xr = x@Wr+br.
  // thread = (h = lane, node-group = wave).  Weights live in registers
  // (8 b128 LDS reads once); x-reads are wave-broadcasts from scratchX;
  // outputs written as b128 vectors.  FMA order per output == old version.
  {
    const int h = tid & 63, ng = tid >> 6;        // ng == wave id (uniform)
    f32x4 wl4[4], wr4[4];
    #pragma unroll
    for (int f4 = 0; f4 < 4; f4++) {
      wl4[f4] = *(const f32x4*)&WlT[h * 20 + f4 * 4];
      wr4[f4] = *(const f32x4*)&WrT[h * 20 + f4 * 4];
    }
    const float blh = bls[h], brh = brs[h];
    float al8[8], ar8[8];
    #pragma unroll
    for (int t = 0; t < 8; t++) {
      const int n = ng * 8 + t;
      float al = blh, ar = brh;
      #pragma unroll
      for (int f4 = 0; f4 < 4; f4++) {
        const f32x4 xv = *(const f32x4*)&scratchX[n * 16 + f4 * 4];  // broadcast
        #pragma unroll
        for (int f = 0; f < 4; f++) {
          al = fmaf(xv[f], wl4[f4][f], al);
          ar = fmaf(xv[f], wr4[f4][f], ar);
        }
      }
      al8[t] = al; ar8[t] = ar;
    }
    *(f32x4*)&xlT[h * 132 + ng * 8]     = *(f32x4*)&al8[0];
    *(f32x4*)&xlT[h * 132 + ng * 8 + 4] = *(f32x4*)&al8[4];
    *(f32x4*)&xrT[h * 132 + ng * 8]     = *(f32x4*)&ar8[0];
    *(f32x4*)&xrT[h * 132 + ng * 8 + 4] = *(f32x4*)&ar8[4];
    u16 pb[8];
    #pragma unroll
    for (int t = 0; t < 8; t++) pb[t] = f2b(al8[t]);
    *(u16x4*)&xlTb[h * 136 + ng * 8]     = *(u16x4*)&pb[0];
    *(u16x4*)&xlTb[h * 136 + ng * 8 + 4] = *(u16x4*)&pb[4];
  }
  __syncthreads();

  // --- stage 2: cl[n] = att.xl[n], cr[n] = att.xr[n] (1024-thread partials) ---
  {
    const int n = tid & 127, g = tid >> 7;        // g 0..7
    const float* srcT = (g < 4) ? xlT : xrT;
    const int h0 = (g & 3) * 16;
    float s = 0.f;
    #pragma unroll
    for (int hh = 0; hh < 16; hh++)
      s = fmaf(atts[h0 + hh], srcT[(h0 + hh) * 132 + n], s);
    red[g * 128 + n] = s;
  }
  __syncthreads();
  if (tid < 256) {
    const int n = tid & 127;
    const int base = (tid < 128) ? 0 : 4;
    const float s = ((red[base * 128 + n] + red[(base + 1) * 128 + n])
                   + red[(base + 2) * 128 + n]) + red[(base + 3) * 128 + n];
    if (tid < 128) cls[n] = s; else crs[n] = s;
  }
  __syncthreads();

  // --- stage 3: e[i][j] -> esbT[j][i] (bf16).  8x2 tile: i0 wave-uniform
  // (A-reads broadcast), B one b64, att[h] scalar (SGPR). ---
  {
    const int i0 = (tid >> 6) * 8;        // wave-uniform, 0..120
    const int j0 = (tid & 63) * 2;        // 0..126
    float acc[8][2] = {};
    #pragma unroll 8
    for (int h = 0; h < 64; h++) {
      const float ah = att[h];            // uniform -> s_load (SGPR)
      const f32x4 xa0 = *(const f32x4*)&xlT[h * 132 + i0];       // broadcast
      const f32x4 xa1 = *(const f32x4*)&xlT[h * 132 + i0 + 4];   // broadcast
      const f32x2 xb  = *(const f32x2*)&xrT[h * 132 + j0];
      #pragma unroll
      for (int a = 0; a < 4; a++) {
        acc[a][0]     = fmaf(ah, __builtin_fabsf(xa0[a] + xb[0]), acc[a][0]);
        acc[a][1]     = fmaf(ah, __builtin_fabsf(xa0[a] + xb[1]), acc[a][1]);
        acc[4 + a][0] = fmaf(ah, __builtin_fabsf(xa1[a] + xb[0]), acc[4 + a][0]);
        acc[4 + a][1] = fmaf(ah, __builtin_fabsf(xa1[a] + xb[1]), acc[4 + a][1]);
      }
    }
    const float* Vc = V_Adap + (size_t)cidx * 16384;
    float vm[8][2];
    #pragma unroll
    for (int a = 0; a < 8; a++) {
      const f32x2 vc = *(const f32x2*)&Vc[(size_t)(i0 + a) * 128 + j0];
      vm[a][0] = vc[0]; vm[a][1] = vc[1];
    }
    const f32x4 cl0 = *(const f32x4*)&cls[i0];
    const f32x4 cl1 = *(const f32x4*)&cls[i0 + 4];
    float cli[8] = {cl0[0], cl0[1], cl0[2], cl0[3], cl1[0], cl1[1], cl1[2], cl1[3]};
    #pragma unroll
    for (int b = 0; b < 2; b++) {
      const int j = j0 + b;
      const float ej = 0.6f * crs[j];
      u16 pk[8];
      #pragma unroll
      for (int a = 0; a < 8; a++) {
        const int i = i0 + a;
        const float e = ej + 0.6f * cli[a] + 0.4f * acc[a][b];
        // sigmoid(v)/128 > 0.004  <=>  v > ln(0.512/0.488)
        const bool m = (vm[a][b] > 0.04800922f) || (i == j);
        pk[a] = f2b(m ? e : -1e9f);
      }
      *(u16x4*)&esbT[j * 136 + i0]     = *(u16x4*)&pk[0];
      *(u16x4*)&esbT[j * 136 + i0 + 4] = *(u16x4*)&pk[4];
    }
  }
  __syncthreads();

  // --- stage 4: p = exp(e) in-place on esbT rows; row-sum -> inv_s ---
  {
    const int j = tid >> 3, c = tid & 7;
    u16* rp = &esbT[j * 136 + c * 16];
    float ps = 0.f;
    #pragma unroll
    for (int half = 0; half < 2; half++) {
      u32x4 q = *(u32x4*)(rp + half * 8);
      #pragma unroll
      for (int w2 = 0; w2 < 4; w2++) {
        const float p0 = __expf(b2f_lo(q[w2]));
        const float p1 = __expf(b2f_hi(q[w2]));
        ps += p0 + p1;
        q[w2] = (unsigned)f2b(p0) | ((unsigned)f2b(p1) << 16);
      }
      *(u32x4*)(rp + half * 8) = q;
    }
    red[c * 128 + j] = ps;
  }
  __syncthreads();
  if (tid < 128) {
    float s = 0.f;
    #pragma unroll
    for (int c = 0; c < 8; c++) s += red[c * 128 + tid];
    inv_s[tid] = 1.f / s;
  }
  __syncthreads();

  // --- stage 5: agg[j][h] = (1/s_j) sum_i p^T[j][i] xl[i][h]  via MFMA ---
  {
    const int w = tid >> 6, lane = tid & 63;
    const int lq = lane >> 4, lr = lane & 15;
    const int jt = w >> 1, ht0 = (w & 1) * 2;
    f32x4 acc2[2] = {};
    #pragma unroll
    for (int ks = 0; ks < 4; ks++) {
      const bf16x8 af = __builtin_bit_cast(bf16x8,
          *(const u32x4*)&esbT[(jt * 16 + lr) * 136 + ks * 32 + lq * 8]);
      #pragma unroll
      for (int t = 0; t < 2; t++) {
        const bf16x8 bfb = __builtin_bit_cast(bf16x8,
            *(const u32x4*)&xlTb[((ht0 + t) * 16 + lr) * 136 + ks * 32 + lq * 8]);
        acc2[t] = __builtin_amdgcn_mfma_f32_16x16x32_bf16(af, bfb, acc2[t], 0, 0, 0);
      }
    }
    #pragma unroll
    for (int t = 0; t < 2; t++) {
      const int h = (ht0 + t) * 16 + lr;
      const float gb = gbias[h];
      #pragma unroll
      for (int r = 0; r < 4; r++) {
        const int j = jt * 16 + lq * 4 + r;
        aggb[j * 72 + h] = f2b(acc2[t][r] * inv_s[j] + gb);
      }
    }
  }
  __syncthreads();

  // --- stage 6: out = agg @ Wfc + bfc -> h (fp32 + bf16) ---
  {
    const int j = tid >> 3, s0 = (tid & 7) * 2;
    float o0 = bfcs[s0], o1 = bfcs[s0 + 1];
    #pragma unroll
    for (int h8 = 0; h8 < 8; h8++) {
      u32x4 q = *(const u32x4*)&aggb[j * 72 + h8 * 8];
      #pragma unroll
      for (int w2 = 0; w2 < 4; w2++) {
        const int h = h8 * 8 + w2 * 2;
        const float a0 = b2f_lo(q[w2]);
        const float a1 = b2f_hi(q[w2]);
        o0 = fmaf(a0, WfcT[s0 * 66 + h], o0);
        o1 = fmaf(a0, WfcT[(s0 + 1) * 66 + h], o1);
        o0 = fmaf(a1, WfcT[s0 * 66 + h + 1], o0);
        o1 = fmaf(a1, WfcT[(s0 + 1) * 66 + h + 1], o1);
      }
    }
    const size_t off = (size_t)bt * 2048 + j * 16 + s0;
    h_f32[off] = o0; h_f32[off + 1] = o1;
    h_b16[off] = f2b(o0); h_b16[off + 1] = f2b(o1);
  }
}

// ---------------------------------------------------------------------------
// transpose + cast: src (2048 x 2048) fp32 row-major -> dst bf16 (dst[n][k] =
// src[k][n]).  Up to 3 matrices via blockIdx.z.
// ---------------------------------------------------------------------------
struct TransArgs {
  const float* s0; const float* s1; const float* s2;
  u16* d0; u16* d1; u16* d2;
};

__global__ __launch_bounds__(256) void transpose_cast(TransArgs p)
{
  const float* src = (blockIdx.z == 0) ? p.s0 : (blockIdx.z == 1) ? p.s1 : p.s2;
  u16* dst = (blockIdx.z == 0) ? p.d0 : (blockIdx.z == 1) ? p.d1 : p.d2;
  __shared__ u16 tile[64][66];
  const int k0 = blockIdx.y * 64, n0 = blockIdx.x * 64;
  const int tid = threadIdx.x;
  const int c = tid & 63, rb = tid >> 6;
  #pragma unroll
  for (int r = 0; r < 16; r++) {
    const int k = rb + r * 4;
    tile[k][c] = f2b(src[(size_t)(k0 + k) * 2048 + n0 + c]);
  }
  __syncthreads();
  #pragma unroll
  for (int r = 0; r < 16; r++) {
    const int n = rb + r * 4;
    dst[(size_t)(n0 + n) * 2048 + k0 + c] = tile[c][n];
  }
}

// ---------------------------------------------------------------------------
// bf16 MFMA GEMM: C[m][n] = sum_k A[m][k] * Bt[n][k] + bias[n]
// 1-deep double-buffered pipeline; LDS XOR-swizzle (pre-swizzled global source
// col + swizzled ds_read col; linear gload_lds dest).
// MODE 0: fp32 out ; 1: bf16 out ; 2: bf16 + relu
// ---------------------------------------------------------------------------
struct GemmArgs {
  const u16* A;
  const u16* Bt0; const u16* Bt1; const u16* Bt2;
  const float* b0; const float* b1; const float* b2;
  void* C0; void* C1; void* C2;
  int N; int K;
};

// 128x128 tile, BK=32, dbuf (32KB LDS -> all 768 QKV blocks co-resident).
template <int MODE>
__global__ __launch_bounds__(256) void gemm_bt(GemmArgs g)
{
  const int z = blockIdx.z;
  const u16* Bt = (z == 0) ? g.Bt0 : (z == 1) ? g.Bt1 : g.Bt2;
  const float* bias = (z == 0) ? g.b0 : (z == 1) ? g.b1 : g.b2;
  void* C = (z == 0) ? g.C0 : (z == 1) ? g.C1 : g.C2;
  const int N = g.N, K = g.K;
  const int m0 = blockIdx.y * 128, n0 = blockIdx.x * 128;

  __shared__ __align__(16) u16 As[2][128 * 32];   // 16KB
  __shared__ __align__(16) u16 Bs[2][128 * 32];   // 16KB

  const int tid = threadIdx.x;
  const int lane = tid & 63, w = tid >> 6;
  const int srow = w * 16 + (lane >> 2);
  const int scol = ((lane & 3) ^ ((lane >> 2) & 3)) * 8;
  const u16* gA = g.A + (size_t)(m0 + srow) * K + scol;
  const u16* gB = Bt + (size_t)(n0 + srow) * K + scol;
  const int lbase = (w * 16) * 32;

  const int wm = (w >> 1) * 64, wn = (w & 1) * 64;
  const int lq = lane >> 4, lr = lane & 15;
  const int csw = (lr & 3) << 3;                  // read-side XOR (elements)

  f32x4 acc[4][4] = {};
  const int NT = K >> 5;

  auto stage = [&](int buf, int kt) {
    const int kk = kt << 5;
    #pragma unroll
    for (int c = 0; c < 2; c++) {
      gload_lds16(gA + (size_t)(c * 64) * K + kk, &As[buf][lbase + c * 64 * 32]);
      gload_lds16(gB + (size_t)(c * 64) * K + kk, &Bs[buf][lbase + c * 64 * 32]);
    }
  };
  auto compute = [&](int buf) {
    bf16x8 af[4], bfr[4];
    #pragma unroll
    for (int i = 0; i < 4; i++) {
      af[i] = __builtin_bit_cast(bf16x8,
          *(const u32x4*)&As[buf][(wm + i * 16 + lr) * 32 + ((lq * 8) ^ csw)]);
      bfr[i] = __builtin_bit_cast(bf16x8,
          *(const u32x4*)&Bs[buf][(wn + i * 16 + lr) * 32 + ((lq * 8) ^ csw)]);
    }
    #pragma unroll
    for (int mi = 0; mi < 4; mi++)
      #pragma unroll
      for (int ni = 0; ni < 4; ni++)
        acc[mi][ni] = __builtin_amdgcn_mfma_f32_16x16x32_bf16(af[mi], bfr[ni], acc[mi][ni], 0, 0, 0);
  };

  stage(0, 0);
  __syncthreads();
  int cur = 0;
  for (int kt = 0; kt + 1 < NT; ++kt) {
    stage(cur ^ 1, kt + 1);       // prefetch next K-tile (async, in flight)
    compute(cur);                 // MFMA on current tile hides the latency
    __syncthreads();              // vmcnt(0)+barrier: next tile ready, cur free
    cur ^= 1;
  }
  compute(cur);                   // last tile, no prefetch

  #pragma unroll
  for (int ni = 0; ni < 4; ni++) {
    const int col = n0 + wn + ni * 16 + lr;
    const float bv = bias[col];
    #pragma unroll
    for (int mi = 0; mi < 4; mi++) {
      #pragma unroll
      for (int r = 0; r < 4; r++) {
        const int row = m0 + wm + mi * 16 + lq * 4 + r;
        float v = acc[mi][ni][r] + bv;
        if (MODE == 0) {
          ((float*)C)[(size_t)row * N + col] = v;
        } else {
          if (MODE == 2) v = fmaxf(v, 0.f);
          ((u16*)C)[(size_t)row * N + col] = f2b(v);
        }
      }
    }
  }
}

// 128(M) x 64(N) tile, BK=64, dbuf (48KB LDS): grid (N/64, M/128) = 512 blocks.
template <int MODE>
__global__ __launch_bounds__(256) void gemm_bt64(GemmArgs g)
{
  const u16* Bt = g.Bt0;
  const float* bias = g.b0;
  void* C = g.C0;
  const int N = g.N, K = g.K;
  const int m0 = blockIdx.y * 128, n0 = blockIdx.x * 64;

  __shared__ __align__(16) u16 As[2][128 * 64];   // 32KB
  __shared__ __align__(16) u16 Bs[2][64 * 64];    // 16KB

  const int tid = threadIdx.x;
  const int lane = tid & 63, w = tid >> 6;
  const int srow = w * 8 + (lane >> 3);
  const int scol = ((lane & 7) ^ (lane >> 3)) * 8;   // pre-swizzled global col
  const u16* gA = g.A + (size_t)(m0 + srow) * K + scol;
  const u16* gB = Bt + (size_t)(n0 + srow) * K + scol;
  const int lbase = (w * 8) * 64;

  const int wm = w * 32;
  const int lq = lane >> 4, lr = lane & 15;
  const int csw = (lr & 7) << 3;                  // read-side XOR (elements)

  f32x4 acc[2][4] = {};
  const int NT = K >> 6;

  auto stage = [&](int buf, int kt) {
    const int kk = kt << 6;
    #pragma unroll
    for (int c = 0; c < 4; c++)
      gload_lds16(gA + (size_t)(c * 32) * K + kk, &As[buf][lbase + c * 32 * 64]);
    #pragma unroll
    for (int c = 0; c < 2; c++)
      gload_lds16(gB + (size_t)(c * 32) * K + kk, &Bs[buf][lbase + c * 32 * 64]);
  };
  auto compute = [&](int buf) {
    #pragma unroll
    for (int ks = 0; ks < 2; ks++) {
      bf16x8 af[2], bfr[4];
      #pragma unroll
      for (int i = 0; i < 2; i++)
        af[i] = __builtin_bit_cast(bf16x8,
            *(const u32x4*)&As[buf][(wm + i * 16 + lr) * 64 + ((ks * 32 + lq * 8) ^ csw)]);
      #pragma unroll
      for (int i = 0; i < 4; i++)
        bfr[i] = __builtin_bit_cast(bf16x8,
            *(const u32x4*)&Bs[buf][(i * 16 + lr) * 64 + ((ks * 32 + lq * 8) ^ csw)]);
      #pragma unroll
      for (int mi = 0; mi < 2; mi++)
        #pragma unroll
        for (int ni = 0; ni < 4; ni++)
          acc[mi][ni] = __builtin_amdgcn_mfma_f32_16x16x32_bf16(af[mi], bfr[ni], acc[mi][ni], 0, 0, 0);
    }
  };

  stage(0, 0);
  __syncthreads();
  int cur = 0;
  for (int kt = 0; kt + 1 < NT; ++kt) {
    stage(cur ^ 1, kt + 1);
    compute(cur);
    __syncthreads();
    cur ^= 1;
  }
  compute(cur);

  #pragma unroll
  for (int ni = 0; ni < 4; ni++) {
    const int col = n0 + ni * 16 + lr;
    const float bv = bias[col];
    #pragma unroll
    for (int mi = 0; mi < 2; mi++) {
      #pragma unroll
      for (int r = 0; r < 4; r++) {
        const int row = m0 + wm + mi * 16 + lq * 4 + r;
        float v = acc[mi][ni][r] + bv;
        if (MODE == 0) {
          ((float*)C)[(size_t)row * N + col] = v;
        } else {
          if (MODE == 2) v = fmaxf(v, 0.f);
          ((u16*)C)[(size_t)row * N + col] = f2b(v);
        }
      }
    }
  }
}

// ---------------------------------------------------------------------------
// attention: one block per (head, batch).  S=64, DH=128, fp32 softmax in LDS.
// ---------------------------------------------------------------------------
__global__ __launch_bounds__(256) void attn_kernel(
    const u16* __restrict__ Qb, const u16* __restrict__ Kb,
    const u16* __restrict__ Vb, u16* __restrict__ AOb)
{
  const int head = blockIdx.x, b = blockIdx.y;
  const int tid = threadIdx.x;
  __shared__ __align__(16) float qs[64 * 132];
  __shared__ __align__(16) float ks[64 * 132];
  __shared__ __align__(16) float vs[64 * 128];
  __shared__ __align__(16) float ss[64 * 65];
  const size_t base = ((size_t)b * 64) * 2048 + (size_t)head * 128;

  for (int idx = tid; idx < 1024; idx += 256) {
    const int t_ = idx >> 4, d8 = (idx & 15) * 8;
    const size_t gp = base + (size_t)t_ * 2048 + d8;
    const u32x4 q = *(const u32x4*)(Qb + gp);
    const u32x4 k = *(const u32x4*)(Kb + gp);
    const u32x4 v = *(const u32x4*)(Vb + gp);
    f32x4 q0 = {b2f_lo(q[0]), b2f_hi(q[0]), b2f_lo(q[1]), b2f_hi(q[1])};
    f32x4 q1 = {b2f_lo(q[2]), b2f_hi(q[2]), b2f_lo(q[3]), b2f_hi(q[3])};
    f32x4 k0 = {b2f_lo(k[0]), b2f_hi(k[0]), b2f_lo(k[1]), b2f_hi(k[1])};
    f32x4 k1 = {b2f_lo(k[2]), b2f_hi(k[2]), b2f_lo(k[3]), b2f_hi(k[3])};
    f32x4 v0 = {b2f_lo(v[0]), b2f_hi(v[0]), b2f_lo(v[1]), b2f_hi(v[1])};
    f32x4 v1 = {b2f_lo(v[2]), b2f_hi(v[2]), b2f_lo(v[3]), b2f_hi(v[3])};
    *(f32x4*)&qs[t_ * 132 + d8] = q0; *(f32x4*)&qs[t_ * 132 + d8 + 4] = q1;
    *(f32x4*)&ks[t_ * 132 + d8] = k0; *(f32x4*)&ks[t_ * 132 + d8 + 4] = k1;
    *(f32x4*)&vs[t_ * 128 + d8] = v0; *(f32x4*)&vs[t_ * 128 + d8 + 4] = v1;
  }
  __syncthreads();

  {
    const int i0 = (tid >> 4) * 4, j0 = tid & 15;
    float acc[4][4] = {};
    #pragma unroll 2
    for (int d0 = 0; d0 < 128; d0 += 4) {
      f32x4 qv[4], kv[4];
      #pragma unroll
      for (int a = 0; a < 4; a++) qv[a] = *(const f32x4*)&qs[(i0 + a) * 132 + d0];
      #pragma unroll
      for (int c = 0; c < 4; c++) kv[c] = *(const f32x4*)&ks[(j0 + c * 16) * 132 + d0];
      #pragma unroll
      for (int a = 0; a < 4; a++)
        #pragma unroll
        for (int c = 0; c < 4; c++)
          #pragma unroll
          for (int e = 0; e < 4; e++)
            acc[a][c] = fmaf(qv[a][e], kv[c][e], acc[a][c]);
    }
    const float sc = 0.08838834764831845f;  // 1/sqrt(128)
    #pragma unroll
    for (int a = 0; a < 4; a++)
      #pragma unroll
      for (int c = 0; c < 4; c++)
        ss[(i0 + a) * 65 + j0 + c * 16] = acc[a][c] * sc;
  }
  __syncthreads();

  {
    const int row = tid >> 2;
    float* rp = &ss[row * 65 + (tid & 3) * 16];
    float mx = -3e38f;
    #pragma unroll
    for (int j = 0; j < 16; j++) mx = fmaxf(mx, rp[j]);
    mx = fmaxf(mx, __shfl_xor(mx, 1, 64));
    mx = fmaxf(mx, __shfl_xor(mx, 2, 64));
    float s = 0.f;
    #pragma unroll
    for (int j = 0; j < 16; j++) { const float p = __expf(rp[j] - mx); rp[j] = p; s += p; }
    s += __shfl_xor(s, 1, 64);
    s += __shfl_xor(s, 2, 64);
    const float inv = 1.f / s;
    #pragma unroll
    for (int j = 0; j < 16; j++) rp[j] *= inv;
  }
  __syncthreads();

  {
    const int i0 = (tid >> 4) * 4, d0 = (tid & 15) * 8;
    float o[4][8] = {};
    for (int j = 0; j < 64; j++) {
      float pv[4];
      #pragma unroll
      for (int a = 0; a < 4; a++) pv[a] = ss[(i0 + a) * 65 + j];
      f32x4v v0 = *(const f32x4v*)&vs[j * 128 + d0];
      f32x4v v1 = *(const f32x4v*)&vs[j * 128 + d0 + 4];
      float vv[8] = {v0[0], v0[1], v0[2], v0[3], v1[0], v1[1], v1[2], v1[3]};
      #pragma unroll
      for (int a = 0; a < 4; a++)
        #pragma unroll
        for (int c = 0; c < 8; c++)
          o[a][c] = fmaf(pv[a], vv[c], o[a][c]);
    }
    #pragma unroll
    for (int a = 0; a < 4; a++)
      #pragma unroll
      for (int c = 0; c < 8; c++)
        AOb[base + (size_t)(i0 + a) * 2048 + d0 + c] = f2b(o[a][c]);
  }
}

// ---------------------------------------------------------------------------
// fused residual + layernorm: h = LN(hin + delta) ; writes fp32 + bf16
// ---------------------------------------------------------------------------
__global__ __launch_bounds__(256) void ln_kernel(
    const float* __restrict__ hin, const float* __restrict__ delta,
    const float* __restrict__ gamma, const float* __restrict__ beta,
    float* __restrict__ hout, u16* __restrict__ bout_)
{
  const int token = blockIdx.x, tid = threadIdx.x;
  const size_t off = (size_t)token * 2048;
  __shared__ float red[8];
  f32x4 v[2];
  float s = 0.f;
  #pragma unroll
  for (int r = 0; r < 2; r++) {
    const int i = r * 1024 + tid * 4;
    const f32x4 a = *(const f32x4*)(hin + off + i);
    const f32x4 b = *(const f32x4*)(delta + off + i);
    v[r] = a + b;
    s += v[r][0] + v[r][1] + v[r][2] + v[r][3];
  }
  #pragma unroll
  for (int o = 32; o > 0; o >>= 1) s += __shfl_down(s, o, 64);
  if ((tid & 63) == 0) red[tid >> 6] = s;
  __syncthreads();
  const float mean = (red[0] + red[1] + red[2] + red[3]) * (1.f / 2048.f);
  float s2 = 0.f;
  #pragma unroll
  for (int r = 0; r < 2; r++)
    #pragma unroll
    for (int e = 0; e < 4; e++) { const float d = v[r][e] - mean; s2 = fmaf(d, d, s2); }
  #pragma unroll
  for (int o = 32; o > 0; o >>= 1) s2 += __shfl_down(s2, o, 64);
  if ((tid & 63) == 0) red[4 + (tid >> 6)] = s2;
  __syncthreads();
  const float var = (red[4] + red[5] + red[6] + red[7]) * (1.f / 2048.f);
  const float rstd = rsqrtf(var + 1e-5f);
  #pragma unroll
  for (int r = 0; r < 2; r++) {
    const int i = r * 1024 + tid * 4;
    const f32x4 gm = *(const f32x4*)(gamma + i);
    const f32x4 bt = *(const f32x4*)(beta + i);
    f32x4 y;
    u16x4 pb;
    #pragma unroll
    for (int e = 0; e < 4; e++) {
      y[e] = (v[r][e] - mean) * rstd * gm[e] + bt[e];
      pb[e] = f2b(y[e]);
    }
    *(f32x4*)(hout + off + i) = y;
    *(u16x4*)(bout_ + off + i) = pb;
  }
}

// ---------------------------------------------------------------------------
// head: out[b][o] = h[b, T-1, :] . Wout[:, o] + bout[o]
// ---------------------------------------------------------------------------
__global__ __launch_bounds__(256) void final_kernel(
    const float* __restrict__ h, const float* __restrict__ Wout,
    const float* __restrict__ bout, float* __restrict__ out)
{
  const int b = blockIdx.x, tid = threadIdx.x;
  __shared__ float row[2048];
  __shared__ float part[256];
  const float* hr = h + ((size_t)b * 64 + 63) * 2048;
  for (int i = tid; i < 2048; i += 256) row[i] = hr[i];
  __syncthreads();
  const int o = tid & 15, ch = tid >> 4;
  float s = 0.f;
  if (o < 10) {
    const int i0 = ch * 128;
    for (int i = i0; i < i0 + 128; i++) s = fmaf(row[i], Wout[(size_t)i * 10 + o], s);
  }
  part[tid] = s;
  __syncthreads();
  if (tid < 10) {
    float t = bout[tid];
    for (int c2 = 0; c2 < 16; c2++) t += part[c2 * 16 + tid];
    out[(size_t)b * 10 + tid] = t;
  }
}

// ---------------------------------------------------------------------------
extern "C" void kernel_launch(void* const* d_in, const int* in_sizes, int n_in,
                              void* d_out, int out_size, void* d_ws, size_t ws_size,
                              hipStream_t stream)
{
  const float* X        = (const float*)d_in[0];
  const float* V_Adap   = (const float*)d_in[1];
  const float* Wl       = (const float*)d_in[2];
  const float* bl       = (const float*)d_in[3];
  const float* Wr       = (const float*)d_in[4];
  const float* br       = (const float*)d_in[5];
  const float* att      = (const float*)d_in[6];
  const float* gat_bias = (const float*)d_in[7];
  const float* Wfc      = (const float*)d_in[8];
  const float* bfc      = (const float*)d_in[9];
  const float* Wq       = (const float*)d_in[10];
  const float* bq       = (const float*)d_in[11];
  const float* Wk       = (const float*)d_in[12];
  const float* bk       = (const float*)d_in[13];
  const float* Wv       = (const float*)d_in[14];
  const float* bv       = (const float*)d_in[15];
  const float* Wo       = (const float*)d_in[16];
  const float* bo       = (const float*)d_in[17];
  const float* ln1_g    = (const float*)d_in[18];
  const float* ln1_b    = (const float*)d_in[19];
  const float* W1       = (const float*)d_in[20];
  const float* b1       = (const float*)d_in[21];
  const float* W2       = (const float*)d_in[22];
  const float* b2       = (const float*)d_in[23];
  const float* ln2_g    = (const float*)d_in[24];
  const float* ln2_b    = (const float*)d_in[25];
  const float* WoutP    = (const float*)d_in[26];
  const float* boutP    = (const float*)d_in[27];
  const int*   class_idx = (const int*)d_in[28];

  char* ws = (char*)d_ws;
  const size_t MB = (size_t)1 << 20;
  float* h_f32 = (float*)(ws);               // 16 MB  (B*T, D) fp32
  u16*   h_b16 = (u16*)(ws + 16 * MB);       //  8 MB
  u16*   Qb    = (u16*)(ws + 24 * MB);       //  8 MB
  u16*   Kb    = (u16*)(ws + 32 * MB);       //  8 MB
  u16*   Vb    = (u16*)(ws + 40 * MB);       //  8 MB
  u16*   AOb   = (u16*)(ws + 48 * MB);       //  8 MB
  float* tmp   = (float*)(ws + 56 * MB);     // 16 MB  (proj / ff2) fp32
  u16*   ff1b  = (u16*)(ws + 72 * MB);       //  8 MB
  u16*   Wt0   = (u16*)(ws + 80 * MB);       //  8 MB transposed bf16 weights
  u16*   Wt1   = (u16*)(ws + 88 * MB);       //  8 MB
  u16*   Wt2   = (u16*)(ws + 96 * MB);       //  8 MB   (total 104 MB)

  // 1. GAT over all (b,t) graphs -> h (fp32 + bf16)
  gat_kernel<<<2048, 1024, 0, stream>>>(X, V_Adap, class_idx, Wl, bl, Wr, br,
                                        att, gat_bias, Wfc, bfc, h_f32, h_b16);

  const size_t DD = 2048ull * 2048ull;
  for (int l = 0; l < 2; l++) {
    const size_t wofs = (size_t)l * DD;
    const size_t bofs = (size_t)l * 2048;

    // QKV (batched z=3, 768 blocks, all co-resident at 32KB LDS)
    transpose_cast<<<dim3(32, 32, 3), 256, 0, stream>>>(
        TransArgs{Wq + wofs, Wk + wofs, Wv + wofs, Wt0, Wt1, Wt2});
    gemm_bt<1><<<dim3(16, 16, 3), 256, 0, stream>>>(
        GemmArgs{h_b16, Wt0, Wt1, Wt2, bq + bofs, bk + bofs, bv + bofs,
                 Qb, Kb, Vb, 2048, 2048});

    attn_kernel<<<dim3(16, 32), 256, 0, stream>>>(Qb, Kb, Vb, AOb);

    // o / W1 / W2 transposed together (Wt0..2 free once QKV gemm is done)
    transpose_cast<<<dim3(32, 32, 3), 256, 0, stream>>>(
        TransArgs{Wo + wofs, W1 + wofs, W2 + wofs, Wt0, Wt1, Wt2});

    // out-proj (128x64 tiles, 512 blocks)
    gemm_bt64<0><<<dim3(32, 16), 256, 0, stream>>>(
        GemmArgs{AOb, Wt0, nullptr, nullptr, bo + bofs, nullptr, nullptr,
                 tmp, nullptr, nullptr, 2048, 2048});
    ln_kernel<<<2048, 256, 0, stream>>>(h_f32, tmp, ln1_g + bofs, ln1_b + bofs,
                                        h_f32, h_b16);

    // FF1 (relu, bf16 out)
    gemm_bt64<2><<<dim3(32, 16), 256, 0, stream>>>(
        GemmArgs{h_b16, Wt1, nullptr, nullptr, b1 + bofs, nullptr, nullptr,
                 ff1b, nullptr, nullptr, 2048, 2048});

    // FF2
    gemm_bt64<0><<<dim3(32, 16), 256, 0, stream>>>(
        GemmArgs{ff1b, Wt2, nullptr, nullptr, b2 + bofs, nullptr, nullptr,
                 tmp, nullptr, nullptr, 2048, 2048});
    ln_kernel<<<2048, 256, 0, stream>>>(h_f32, tmp, ln2_g + bofs, ln2_b + bofs,
                                        h_f32, h_b16);
  }

  final_kernel<<<32, 256, 0, stream>>>(h_f32, WoutP, boutP, (float*)d_out);
}

// Round 4
// 874.374 us; speedup vs baseline: 1.1053x; 1.0190x over previous
//
#include <hip/hip_runtime.h>
#include <cstdint>
#include <cstddef>

// ---------------------------------------------------------------------------
// FullyDynamicSTGNN: GAT(128 nodes, T=64, B=32) -> 2-layer Transformer(d=2048)
// -> linear head.  Heavy GEMMs in bf16 MFMA (16x16x32), everything else fp32.
// R7: GEMM pipeline fixed.  R4's dbuf drained vmcnt(0) at the barrier right
//     after issuing the prefetch (syncthreads semantics) -> loads never hid.
//     Now: 3-buffer ring, counted s_waitcnt vmcnt(2L/L/0), raw s_barrier pair,
//     setprio(1) around compute.  Loads get TWO compute phases to land.
//     vmcnt FIFO-retire => <=2L outstanding == buffer kt complete; barrier A
//     publishes it block-wide; barrier B guards buffer reuse (kt+3 == kt mod 3).
//     GAT / attn / ln / transpose byte-identical to R6 (single-variable).
// ---------------------------------------------------------------------------

typedef unsigned short u16;
typedef __bf16 bf16x8 __attribute__((ext_vector_type(8)));
typedef float f32x4 __attribute__((ext_vector_type(4)));
typedef float f32x2 __attribute__((ext_vector_type(2)));
typedef unsigned int u32x4 __attribute__((ext_vector_type(4)));
typedef float f32x4v __attribute__((ext_vector_type(4)));
typedef unsigned short u16x4 __attribute__((ext_vector_type(4)));

__device__ __forceinline__ u16 f2b(float f) {
  union { float f; unsigned u; } x; x.f = f;
  unsigned r = x.u + 0x7fffu + ((x.u >> 16) & 1u);   // RNE
  return (u16)(r >> 16);
}
__device__ __forceinline__ float b2f(u16 s) {
  union { unsigned u; float f; } x; x.u = ((unsigned)s) << 16;
  return x.f;
}
__device__ __forceinline__ float b2f_lo(unsigned q) {
  union { unsigned u; float f; } x; x.u = q << 16;
  return x.f;
}
__device__ __forceinline__ float b2f_hi(unsigned q) {
  union { unsigned u; float f; } x; x.u = q & 0xffff0000u;
  return x.f;
}

// async global->LDS, 16B per lane; lds dest must be wave-uniform base (+lane*16)
__device__ __forceinline__ void gload_lds16(const void* g, void* l) {
  __builtin_amdgcn_global_load_lds(
      (const __attribute__((address_space(1))) unsigned int*)g,
      (__attribute__((address_space(3))) unsigned int*)l, 16, 0, 0);
}

// ---------------------------------------------------------------------------
// GAT kernel: one 1024-thread block per (b,t) graph.  (unchanged from R6)
// ---------------------------------------------------------------------------
__global__ __launch_bounds__(1024) void gat_kernel(
    const float* __restrict__ X, const float* __restrict__ V_Adap,
    const int* __restrict__ class_idx,
    const float* __restrict__ Wl, const float* __restrict__ bl,
    const float* __restrict__ Wr, const float* __restrict__ br,
    const float* __restrict__ att, const float* __restrict__ gat_bias,
    const float* __restrict__ Wfc, const float* __restrict__ bfc,
    float* __restrict__ h_f32, u16* __restrict__ h_b16)
{
  const int bt = blockIdx.x;
  const int tid = threadIdx.x;

  __shared__ __align__(16) float xlT[64 * 132];     // 33792
  __shared__ __align__(16) float xrT[64 * 132];     // 33792
  __shared__ __align__(16) u16   xlTb[64 * 136];    // 17408
  __shared__ __align__(16) u16   esbT[128 * 136];   // 34816
  __shared__ __align__(16) u16   aggb[128 * 72];    // 18432 (also X scratch)
  __shared__ __align__(16) float WlT[64 * 20];      // 5120  [h][f]
  __shared__ __align__(16) float WrT[64 * 20];      // 5120
  __shared__ __align__(16) float WfcT[16 * 66];     // 4224  [s][h]
  __shared__ float atts[64], bls[64], brs[64], gbias[64], bfcs[16];
  __shared__ float cls[128], crs[128], inv_s[128];
  __shared__ float red[8 * 128];                    // 4096

  float* scratchX = (float*)aggb;   // 8KB of 18KB; aggb unused until stage 5

  // --- stage 0: load weights + stage X row-block into LDS ---
  {
    const int h = tid >> 4, f = tid & 15;
    WlT[h * 20 + f] = Wl[f * 64 + h];
    WrT[h * 20 + f] = Wr[f * 64 + h];
    WfcT[f * 66 + h] = Wfc[h * 16 + f];    // f plays 's' here
  }
  if (tid < 64) { atts[tid] = att[tid]; bls[tid] = bl[tid]; brs[tid] = br[tid]; gbias[tid] = gat_bias[tid]; }
  if (tid < 16) bfcs[tid] = bfc[tid];
  if (tid < 512)
    ((f32x4*)scratchX)[tid] = ((const f32x4*)(X + (size_t)bt * 2048))[tid];
  const int cidx = *class_idx;
  __syncthreads();

  // --- stage 1: xl = x@Wl+bl, xr = x@Wr+br.  (h = lane, node-group = wave) ---
  {
    const int h = tid & 63, ng = tid >> 6;        // ng == wave id (uniform)
    f32x4 wl4[4], wr4[4];
    #pragma unroll
    for (int f4 = 0; f4 < 4; f4++) {
      wl4[f4] = *(const f32x4*)&WlT[h * 20 + f4 * 4];
      wr4[f4] = *(const f32x4*)&WrT[h * 20 + f4 * 4];
    }
    const float blh = bls[h], brh = brs[h];
    float al8[8], ar8[8];
    #pragma unroll
    for (int t = 0; t < 8; t++) {
      const int n = ng * 8 + t;
      float al = blh, ar = brh;
      #pragma unroll
      for (int f4 = 0; f4 < 4; f4++) {
        const f32x4 xv = *(const f32x4*)&scratchX[n * 16 + f4 * 4];  // broadcast
        #pragma unroll
        for (int f = 0; f < 4; f++) {
          al = fmaf(xv[f], wl4[f4][f], al);
          ar = fmaf(xv[f], wr4[f4][f], ar);
        }
      }
      al8[t] = al; ar8[t] = ar;
    }
    *(f32x4*)&xlT[h * 132 + ng * 8]     = *(f32x4*)&al8[0];
    *(f32x4*)&xlT[h * 132 + ng * 8 + 4] = *(f32x4*)&al8[4];
    *(f32x4*)&xrT[h * 132 + ng * 8]     = *(f32x4*)&ar8[0];
    *(f32x4*)&xrT[h * 132 + ng * 8 + 4] = *(f32x4*)&ar8[4];
    u16 pb[8];
    #pragma unroll
    for (int t = 0; t < 8; t++) pb[t] = f2b(al8[t]);
    *(u16x4*)&xlTb[h * 136 + ng * 8]     = *(u16x4*)&pb[0];
    *(u16x4*)&xlTb[h * 136 + ng * 8 + 4] = *(u16x4*)&pb[4];
  }
  __syncthreads();

  // --- stage 2: cl[n] = att.xl[n], cr[n] = att.xr[n] (1024-thread partials) ---
  {
    const int n = tid & 127, g = tid >> 7;        // g 0..7
    const float* srcT = (g < 4) ? xlT : xrT;
    const int h0 = (g & 3) * 16;
    float s = 0.f;
    #pragma unroll
    for (int hh = 0; hh < 16; hh++)
      s = fmaf(atts[h0 + hh], srcT[(h0 + hh) * 132 + n], s);
    red[g * 128 + n] = s;
  }
  __syncthreads();
  if (tid < 256) {
    const int n = tid & 127;
    const int base = (tid < 128) ? 0 : 4;
    const float s = ((red[base * 128 + n] + red[(base + 1) * 128 + n])
                   + red[(base + 2) * 128 + n]) + red[(base + 3) * 128 + n];
    if (tid < 128) cls[n] = s; else crs[n] = s;
  }
  __syncthreads();

  // --- stage 3: e[i][j] -> esbT[j][i] (bf16).  8x2 tile, i0 wave-uniform ---
  {
    const int i0 = (tid >> 6) * 8;        // wave-uniform, 0..120
    const int j0 = (tid & 63) * 2;        // 0..126
    float acc[8][2] = {};
    #pragma unroll 8
    for (int h = 0; h < 64; h++) {
      const float ah = att[h];            // uniform -> s_load (SGPR)
      const f32x4 xa0 = *(const f32x4*)&xlT[h * 132 + i0];       // broadcast
      const f32x4 xa1 = *(const f32x4*)&xlT[h * 132 + i0 + 4];   // broadcast
      const f32x2 xb  = *(const f32x2*)&xrT[h * 132 + j0];
      #pragma unroll
      for (int a = 0; a < 4; a++) {
        acc[a][0]     = fmaf(ah, __builtin_fabsf(xa0[a] + xb[0]), acc[a][0]);
        acc[a][1]     = fmaf(ah, __builtin_fabsf(xa0[a] + xb[1]), acc[a][1]);
        acc[4 + a][0] = fmaf(ah, __builtin_fabsf(xa1[a] + xb[0]), acc[4 + a][0]);
        acc[4 + a][1] = fmaf(ah, __builtin_fabsf(xa1[a] + xb[1]), acc[4 + a][1]);
      }
    }
    const float* Vc = V_Adap + (size_t)cidx * 16384;
    float vm[8][2];
    #pragma unroll
    for (int a = 0; a < 8; a++) {
      const f32x2 vc = *(const f32x2*)&Vc[(size_t)(i0 + a) * 128 + j0];
      vm[a][0] = vc[0]; vm[a][1] = vc[1];
    }
    const f32x4 cl0 = *(const f32x4*)&cls[i0];
    const f32x4 cl1 = *(const f32x4*)&cls[i0 + 4];
    float cli[8] = {cl0[0], cl0[1], cl0[2], cl0[3], cl1[0], cl1[1], cl1[2], cl1[3]};
    #pragma unroll
    for (int b = 0; b < 2; b++) {
      const int j = j0 + b;
      const float ej = 0.6f * crs[j];
      u16 pk[8];
      #pragma unroll
      for (int a = 0; a < 8; a++) {
        const int i = i0 + a;
        const float e = ej + 0.6f * cli[a] + 0.4f * acc[a][b];
        // sigmoid(v)/128 > 0.004  <=>  v > ln(0.512/0.488)
        const bool m = (vm[a][b] > 0.04800922f) || (i == j);
        pk[a] = f2b(m ? e : -1e9f);
      }
      *(u16x4*)&esbT[j * 136 + i0]     = *(u16x4*)&pk[0];
      *(u16x4*)&esbT[j * 136 + i0 + 4] = *(u16x4*)&pk[4];
    }
  }
  __syncthreads();

  // --- stage 4: p = exp(e) in-place on esbT rows; row-sum -> inv_s ---
  {
    const int j = tid >> 3, c = tid & 7;
    u16* rp = &esbT[j * 136 + c * 16];
    float ps = 0.f;
    #pragma unroll
    for (int half = 0; half < 2; half++) {
      u32x4 q = *(u32x4*)(rp + half * 8);
      #pragma unroll
      for (int w2 = 0; w2 < 4; w2++) {
        const float p0 = __expf(b2f_lo(q[w2]));
        const float p1 = __expf(b2f_hi(q[w2]));
        ps += p0 + p1;
        q[w2] = (unsigned)f2b(p0) | ((unsigned)f2b(p1) << 16);
      }
      *(u32x4*)(rp + half * 8) = q;
    }
    red[c * 128 + j] = ps;
  }
  __syncthreads();
  if (tid < 128) {
    float s = 0.f;
    #pragma unroll
    for (int c = 0; c < 8; c++) s += red[c * 128 + tid];
    inv_s[tid] = 1.f / s;
  }
  __syncthreads();

  // --- stage 5: agg[j][h] = (1/s_j) sum_i p^T[j][i] xl[i][h]  via MFMA ---
  {
    const int w = tid >> 6, lane = tid & 63;
    const int lq = lane >> 4, lr = lane & 15;
    const int jt = w >> 1, ht0 = (w & 1) * 2;
    f32x4 acc2[2] = {};
    #pragma unroll
    for (int ks = 0; ks < 4; ks++) {
      const bf16x8 af = __builtin_bit_cast(bf16x8,
          *(const u32x4*)&esbT[(jt * 16 + lr) * 136 + ks * 32 + lq * 8]);
      #pragma unroll
      for (int t = 0; t < 2; t++) {
        const bf16x8 bfb = __builtin_bit_cast(bf16x8,
            *(const u32x4*)&xlTb[((ht0 + t) * 16 + lr) * 136 + ks * 32 + lq * 8]);
        acc2[t] = __builtin_amdgcn_mfma_f32_16x16x32_bf16(af, bfb, acc2[t], 0, 0, 0);
      }
    }
    #pragma unroll
    for (int t = 0; t < 2; t++) {
      const int h = (ht0 + t) * 16 + lr;
      const float gb = gbias[h];
      #pragma unroll
      for (int r = 0; r < 4; r++) {
        const int j = jt * 16 + lq * 4 + r;
        aggb[j * 72 + h] = f2b(acc2[t][r] * inv_s[j] + gb);
      }
    }
  }
  __syncthreads();

  // --- stage 6: out = agg @ Wfc + bfc -> h (fp32 + bf16) ---
  {
    const int j = tid >> 3, s0 = (tid & 7) * 2;
    float o0 = bfcs[s0], o1 = bfcs[s0 + 1];
    #pragma unroll
    for (int h8 = 0; h8 < 8; h8++) {
      u32x4 q = *(const u32x4*)&aggb[j * 72 + h8 * 8];
      #pragma unroll
      for (int w2 = 0; w2 < 4; w2++) {
        const int h = h8 * 8 + w2 * 2;
        const float a0 = b2f_lo(q[w2]);
        const float a1 = b2f_hi(q[w2]);
        o0 = fmaf(a0, WfcT[s0 * 66 + h], o0);
        o1 = fmaf(a0, WfcT[(s0 + 1) * 66 + h], o1);
        o0 = fmaf(a1, WfcT[s0 * 66 + h + 1], o0);
        o1 = fmaf(a1, WfcT[(s0 + 1) * 66 + h + 1], o1);
      }
    }
    const size_t off = (size_t)bt * 2048 + j * 16 + s0;
    h_f32[off] = o0; h_f32[off + 1] = o1;
    h_b16[off] = f2b(o0); h_b16[off + 1] = f2b(o1);
  }
}

// ---------------------------------------------------------------------------
// transpose + cast: src (2048 x 2048) fp32 row-major -> dst bf16 (dst[n][k] =
// src[k][n]).  Up to 3 matrices via blockIdx.z.
// ---------------------------------------------------------------------------
struct TransArgs {
  const float* s0; const float* s1; const float* s2;
  u16* d0; u16* d1; u16* d2;
};

__global__ __launch_bounds__(256) void transpose_cast(TransArgs p)
{
  const float* src = (blockIdx.z == 0) ? p.s0 : (blockIdx.z == 1) ? p.s1 : p.s2;
  u16* dst = (blockIdx.z == 0) ? p.d0 : (blockIdx.z == 1) ? p.d1 : p.d2;
  __shared__ u16 tile[64][66];
  const int k0 = blockIdx.y * 64, n0 = blockIdx.x * 64;
  const int tid = threadIdx.x;
  const int c = tid & 63, rb = tid >> 6;
  #pragma unroll
  for (int r = 0; r < 16; r++) {
    const int k = rb + r * 4;
    tile[k][c] = f2b(src[(size_t)(k0 + k) * 2048 + n0 + c]);
  }
  __syncthreads();
  #pragma unroll
  for (int r = 0; r < 16; r++) {
    const int n = rb + r * 4;
    dst[(size_t)(n0 + n) * 2048 + k0 + c] = tile[c][n];
  }
}

// ---------------------------------------------------------------------------
// bf16 MFMA GEMM: C[m][n] = sum_k A[m][k] * Bt[n][k] + bias[n]
// R7: 3-buffer ring, counted vmcnt, raw barriers.
//   prologue: stage(b0,k0), stage(b1,k1)
//   iter kt : stage(b[kt+2 mod 3], kt+2)        (loads span 2 compute phases)
//             s_waitcnt vmcnt(2L) -> kt's L loads retired (FIFO)
//             s_barrier            -> buffer kt complete block-wide
//             setprio(1) compute(kt) setprio(0)
//             s_barrier            -> safe to overwrite buf kt next iter (+3)
// LDS XOR-swizzle as before (pre-swizzled global source col + swizzled read).
// MODE 0: fp32 out ; 1: bf16 out ; 2: bf16 + relu
// ---------------------------------------------------------------------------
struct GemmArgs {
  const u16* A;
  const u16* Bt0; const u16* Bt1; const u16* Bt2;
  const float* b0; const float* b1; const float* b2;
  void* C0; void* C1; void* C2;
  int N; int K;
};

// 128x128 tile, BK=32, 3-buf (48KB LDS -> 3 blocks/CU, 768-block grid resident).
// L = 4 gload_lds per stage per wave -> vmcnt 8/4/0.
template <int MODE>
__global__ __launch_bounds__(256) void gemm_bt(GemmArgs g)
{
  const int z = blockIdx.z;
  const u16* Bt = (z == 0) ? g.Bt0 : (z == 1) ? g.Bt1 : g.Bt2;
  const float* bias = (z == 0) ? g.b0 : (z == 1) ? g.b1 : g.b2;
  void* C = (z == 0) ? g.C0 : (z == 1) ? g.C1 : g.C2;
  const int N = g.N, K = g.K;
  const int m0 = blockIdx.y * 128, n0 = blockIdx.x * 128;

  __shared__ __align__(16) u16 As[3][128 * 32];   // 24KB
  __shared__ __align__(16) u16 Bs[3][128 * 32];   // 24KB

  const int tid = threadIdx.x;
  const int lane = tid & 63, w = tid >> 6;
  const int srow = w * 16 + (lane >> 2);
  const int scol = ((lane & 3) ^ ((lane >> 2) & 3)) * 8;
  const u16* gA = g.A + (size_t)(m0 + srow) * K + scol;
  const u16* gB = Bt + (size_t)(n0 + srow) * K + scol;
  const int lbase = (w * 16) * 32;

  const int wm = (w >> 1) * 64, wn = (w & 1) * 64;
  const int lq = lane >> 4, lr = lane & 15;
  const int csw = (lr & 3) << 3;                  // read-side XOR (elements)

  f32x4 acc[4][4] = {};
  const int NT = K >> 5;

  auto stage = [&](int buf, int kt) {
    const int kk = kt << 5;
    #pragma unroll
    for (int c = 0; c < 2; c++) {
      gload_lds16(gA + (size_t)(c * 64) * K + kk, &As[buf][lbase + c * 64 * 32]);
      gload_lds16(gB + (size_t)(c * 64) * K + kk, &Bs[buf][lbase + c * 64 * 32]);
    }
  };
  auto compute = [&](int buf) {
    bf16x8 af[4], bfr[4];
    #pragma unroll
    for (int i = 0; i < 4; i++) {
      af[i] = __builtin_bit_cast(bf16x8,
          *(const u32x4*)&As[buf][(wm + i * 16 + lr) * 32 + ((lq * 8) ^ csw)]);
      bfr[i] = __builtin_bit_cast(bf16x8,
          *(const u32x4*)&Bs[buf][(wn + i * 16 + lr) * 32 + ((lq * 8) ^ csw)]);
    }
    #pragma unroll
    for (int mi = 0; mi < 4; mi++)
      #pragma unroll
      for (int ni = 0; ni < 4; ni++)
        acc[mi][ni] = __builtin_amdgcn_mfma_f32_16x16x32_bf16(af[mi], bfr[ni], acc[mi][ni], 0, 0, 0);
  };

  stage(0, 0);
  stage(1, 1);
  int cA = 0;                          // buffer holding tile kt
  for (int kt = 0; kt < NT; ++kt) {
    if (kt + 2 < NT) {
      int b2 = cA + 2; if (b2 >= 3) b2 -= 3;
      stage(b2, kt + 2);
      asm volatile("s_waitcnt vmcnt(8)" ::: "memory");
    } else if (kt + 1 < NT) {
      asm volatile("s_waitcnt vmcnt(4)" ::: "memory");
    } else {
      asm volatile("s_waitcnt vmcnt(0)" ::: "memory");
    }
    __builtin_amdgcn_s_barrier();
    asm volatile("" ::: "memory");
    __builtin_amdgcn_s_setprio(1);
    compute(cA);
    __builtin_amdgcn_s_setprio(0);
    asm volatile("" ::: "memory");
    __builtin_amdgcn_s_barrier();
    asm volatile("" ::: "memory");
    if (++cA == 3) cA = 0;
  }

  #pragma unroll
  for (int ni = 0; ni < 4; ni++) {
    const int col = n0 + wn + ni * 16 + lr;
    const float bv = bias[col];
    #pragma unroll
    for (int mi = 0; mi < 4; mi++) {
      #pragma unroll
      for (int r = 0; r < 4; r++) {
        const int row = m0 + wm + mi * 16 + lq * 4 + r;
        float v = acc[mi][ni][r] + bv;
        if (MODE == 0) {
          ((float*)C)[(size_t)row * N + col] = v;
        } else {
          if (MODE == 2) v = fmaxf(v, 0.f);
          ((u16*)C)[(size_t)row * N + col] = f2b(v);
        }
      }
    }
  }
}

// 128(M) x 64(N) tile, BK=64, 3-buf (72KB LDS -> 2 blocks/CU, 512-block grid
// resident).  L = 6 gload_lds per stage per wave -> vmcnt 12/6/0.
template <int MODE>
__global__ __launch_bounds__(256) void gemm_bt64(GemmArgs g)
{
  const u16* Bt = g.Bt0;
  const float* bias = g.b0;
  void* C = g.C0;
  const int N = g.N, K = g.K;
  const int m0 = blockIdx.y * 128, n0 = blockIdx.x * 64;

  __shared__ __align__(16) u16 As[3][128 * 64];   // 48KB
  __shared__ __align__(16) u16 Bs[3][64 * 64];    // 24KB

  const int tid = threadIdx.x;
  const int lane = tid & 63, w = tid >> 6;
  const int srow = w * 8 + (lane >> 3);
  const int scol = ((lane & 7) ^ (lane >> 3)) * 8;   // pre-swizzled global col
  const u16* gA = g.A + (size_t)(m0 + srow) * K + scol;
  const u16* gB = Bt + (size_t)(n0 + srow) * K + scol;
  const int lbase = (w * 8) * 64;

  const int wm = w * 32;
  const int lq = lane >> 4, lr = lane & 15;
  const int csw = (lr & 7) << 3;                  // read-side XOR (elements)

  f32x4 acc[2][4] = {};
  const int NT = K >> 6;

  auto stage = [&](int buf, int kt) {
    const int kk = kt << 6;
    #pragma unroll
    for (int c = 0; c < 4; c++)
      gload_lds16(gA + (size_t)(c * 32) * K + kk, &As[buf][lbase + c * 32 * 64]);
    #pragma unroll
    for (int c = 0; c < 2; c++)
      gload_lds16(gB + (size_t)(c * 32) * K + kk, &Bs[buf][lbase + c * 32 * 64]);
  };
  auto compute = [&](int buf) {
    #pragma unroll
    for (int ks = 0; ks < 2; ks++) {
      bf16x8 af[2], bfr[4];
      #pragma unroll
      for (int i = 0; i < 2; i++)
        af[i] = __builtin_bit_cast(bf16x8,
            *(const u32x4*)&As[buf][(wm + i * 16 + lr) * 64 + ((ks * 32 + lq * 8) ^ csw)]);
      #pragma unroll
      for (int i = 0; i < 4; i++)
        bfr[i] = __builtin_bit_cast(bf16x8,
            *(const u32x4*)&Bs[buf][(i * 16 + lr) * 64 + ((ks * 32 + lq * 8) ^ csw)]);
      #pragma unroll
      for (int mi = 0; mi < 2; mi++)
        #pragma unroll
        for (int ni = 0; ni < 4; ni++)
          acc[mi][ni] = __builtin_amdgcn_mfma_f32_16x16x32_bf16(af[mi], bfr[ni], acc[mi][ni], 0, 0, 0);
    }
  };

  stage(0, 0);
  stage(1, 1);
  int cA = 0;
  for (int kt = 0; kt < NT; ++kt) {
    if (kt + 2 < NT) {
      int b2 = cA + 2; if (b2 >= 3) b2 -= 3;
      stage(b2, kt + 2);
      asm volatile("s_waitcnt vmcnt(12)" ::: "memory");
    } else if (kt + 1 < NT) {
      asm volatile("s_waitcnt vmcnt(6)" ::: "memory");
    } else {
      asm volatile("s_waitcnt vmcnt(0)" ::: "memory");
    }
    __builtin_amdgcn_s_barrier();
    asm volatile("" ::: "memory");
    __builtin_amdgcn_s_setprio(1);
    compute(cA);
    __builtin_amdgcn_s_setprio(0);
    asm volatile("" ::: "memory");
    __builtin_amdgcn_s_barrier();
    asm volatile("" ::: "memory");
    if (++cA == 3) cA = 0;
  }

  #pragma unroll
  for (int ni = 0; ni < 4; ni++) {
    const int col = n0 + ni * 16 + lr;
    const float bv = bias[col];
    #pragma unroll
    for (int mi = 0; mi < 2; mi++) {
      #pragma unroll
      for (int r = 0; r < 4; r++) {
        const int row = m0 + wm + mi * 16 + lq * 4 + r;
        float v = acc[mi][ni][r] + bv;
        if (MODE == 0) {
          ((float*)C)[(size_t)row * N + col] = v;
        } else {
          if (MODE == 2) v = fmaxf(v, 0.f);
          ((u16*)C)[(size_t)row * N + col] = f2b(v);
        }
      }
    }
  }
}

// ---------------------------------------------------------------------------
// attention: one block per (head, batch).  S=64, DH=128, fp32 softmax in LDS.
// ---------------------------------------------------------------------------
__global__ __launch_bounds__(256) void attn_kernel(
    const u16* __restrict__ Qb, const u16* __restrict__ Kb,
    const u16* __restrict__ Vb, u16* __restrict__ AOb)
{
  const int head = blockIdx.x, b = blockIdx.y;
  const int tid = threadIdx.x;
  __shared__ __align__(16) float qs[64 * 132];
  __shared__ __align__(16) float ks[64 * 132];
  __shared__ __align__(16) float vs[64 * 128];
  __shared__ __align__(16) float ss[64 * 65];
  const size_t base = ((size_t)b * 64) * 2048 + (size_t)head * 128;

  for (int idx = tid; idx < 1024; idx += 256) {
    const int t_ = idx >> 4, d8 = (idx & 15) * 8;
    const size_t gp = base + (size_t)t_ * 2048 + d8;
    const u32x4 q = *(const u32x4*)(Qb + gp);
    const u32x4 k = *(const u32x4*)(Kb + gp);
    const u32x4 v = *(const u32x4*)(Vb + gp);
    f32x4 q0 = {b2f_lo(q[0]), b2f_hi(q[0]), b2f_lo(q[1]), b2f_hi(q[1])};
    f32x4 q1 = {b2f_lo(q[2]), b2f_hi(q[2]), b2f_lo(q[3]), b2f_hi(q[3])};
    f32x4 k0 = {b2f_lo(k[0]), b2f_hi(k[0]), b2f_lo(k[1]), b2f_hi(k[1])};
    f32x4 k1 = {b2f_lo(k[2]), b2f_hi(k[2]), b2f_lo(k[3]), b2f_hi(k[3])};
    f32x4 v0 = {b2f_lo(v[0]), b2f_hi(v[0]), b2f_lo(v[1]), b2f_hi(v[1])};
    f32x4 v1 = {b2f_lo(v[2]), b2f_hi(v[2]), b2f_lo(v[3]), b2f_hi(v[3])};
    *(f32x4*)&qs[t_ * 132 + d8] = q0; *(f32x4*)&qs[t_ * 132 + d8 + 4] = q1;
    *(f32x4*)&ks[t_ * 132 + d8] = k0; *(f32x4*)&ks[t_ * 132 + d8 + 4] = k1;
    *(f32x4*)&vs[t_ * 128 + d8] = v0; *(f32x4*)&vs[t_ * 128 + d8 + 4] = v1;
  }
  __syncthreads();

  {
    const int i0 = (tid >> 4) * 4, j0 = tid & 15;
    float acc[4][4] = {};
    #pragma unroll 2
    for (int d0 = 0; d0 < 128; d0 += 4) {
      f32x4 qv[4], kv[4];
      #pragma unroll
      for (int a = 0; a < 4; a++) qv[a] = *(const f32x4*)&qs[(i0 + a) * 132 + d0];
      #pragma unroll
      for (int c = 0; c < 4; c++) kv[c] = *(const f32x4*)&ks[(j0 + c * 16) * 132 + d0];
      #pragma unroll
      for (int a = 0; a < 4; a++)
        #pragma unroll
        for (int c = 0; c < 4; c++)
          #pragma unroll
          for (int e = 0; e < 4; e++)
            acc[a][c] = fmaf(qv[a][e], kv[c][e], acc[a][c]);
    }
    const float sc = 0.08838834764831845f;  // 1/sqrt(128)
    #pragma unroll
    for (int a = 0; a < 4; a++)
      #pragma unroll
      for (int c = 0; c < 4; c++)
        ss[(i0 + a) * 65 + j0 + c * 16] = acc[a][c] * sc;
  }
  __syncthreads();

  {
    const int row = tid >> 2;
    float* rp = &ss[row * 65 + (tid & 3) * 16];
    float mx = -3e38f;
    #pragma unroll
    for (int j = 0; j < 16; j++) mx = fmaxf(mx, rp[j]);
    mx = fmaxf(mx, __shfl_xor(mx, 1, 64));
    mx = fmaxf(mx, __shfl_xor(mx, 2, 64));
    float s = 0.f;
    #pragma unroll
    for (int j = 0; j < 16; j++) { const float p = __expf(rp[j] - mx); rp[j] = p; s += p; }
    s += __shfl_xor(s, 1, 64);
    s += __shfl_xor(s, 2, 64);
    const float inv = 1.f / s;
    #pragma unroll
    for (int j = 0; j < 16; j++) rp[j] *= inv;
  }
  __syncthreads();

  {
    const int i0 = (tid >> 4) * 4, d0 = (tid & 15) * 8;
    float o[4][8] = {};
    for (int j = 0; j < 64; j++) {
      float pv[4];
      #pragma unroll
      for (int a = 0; a < 4; a++) pv[a] = ss[(i0 + a) * 65 + j];
      f32x4v v0 = *(const f32x4v*)&vs[j * 128 + d0];
      f32x4v v1 = *(const f32x4v*)&vs[j * 128 + d0 + 4];
      float vv[8] = {v0[0], v0[1], v0[2], v0[3], v1[0], v1[1], v1[2], v1[3]};
      #pragma unroll
      for (int a = 0; a < 4; a++)
        #pragma unroll
        for (int c = 0; c < 8; c++)
          o[a][c] = fmaf(pv[a], vv[c], o[a][c]);
    }
    #pragma unroll
    for (int a = 0; a < 4; a++)
      #pragma unroll
      for (int c = 0; c < 8; c++)
        AOb[base + (size_t)(i0 + a) * 2048 + d0 + c] = f2b(o[a][c]);
  }
}

// ---------------------------------------------------------------------------
// fused residual + layernorm: h = LN(hin + delta) ; writes fp32 + bf16
// ---------------------------------------------------------------------------
__global__ __launch_bounds__(256) void ln_kernel(
    const float* __restrict__ hin, const float* __restrict__ delta,
    const float* __restrict__ gamma, const float* __restrict__ beta,
    float* __restrict__ hout, u16* __restrict__ bout_)
{
  const int token = blockIdx.x, tid = threadIdx.x;
  const size_t off = (size_t)token * 2048;
  __shared__ float red[8];
  f32x4 v[2];
  float s = 0.f;
  #pragma unroll
  for (int r = 0; r < 2; r++) {
    const int i = r * 1024 + tid * 4;
    const f32x4 a = *(const f32x4*)(hin + off + i);
    const f32x4 b = *(const f32x4*)(delta + off + i);
    v[r] = a + b;
    s += v[r][0] + v[r][1] + v[r][2] + v[r][3];
  }
  #pragma unroll
  for (int o = 32; o > 0; o >>= 1) s += __shfl_down(s, o, 64);
  if ((tid & 63) == 0) red[tid >> 6] = s;
  __syncthreads();
  const float mean = (red[0] + red[1] + red[2] + red[3]) * (1.f / 2048.f);
  float s2 = 0.f;
  #pragma unroll
  for (int r = 0; r < 2; r++)
    #pragma unroll
    for (int e = 0; e < 4; e++) { const float d = v[r][e] - mean; s2 = fmaf(d, d, s2); }
  #pragma unroll
  for (int o = 32; o > 0; o >>= 1) s2 += __shfl_down(s2, o, 64);
  if ((tid & 63) == 0) red[4 + (tid >> 6)] = s2;
  __syncthreads();
  const float var = (red[4] + red[5] + red[6] + red[7]) * (1.f / 2048.f);
  const float rstd = rsqrtf(var + 1e-5f);
  #pragma unroll
  for (int r = 0; r < 2; r++) {
    const int i = r * 1024 + tid * 4;
    const f32x4 gm = *(const f32x4*)(gamma + i);
    const f32x4 bt = *(const f32x4*)(beta + i);
    f32x4 y;
    u16x4 pb;
    #pragma unroll
    for (int e = 0; e < 4; e++) {
      y[e] = (v[r][e] - mean) * rstd * gm[e] + bt[e];
      pb[e] = f2b(y[e]);
    }
    *(f32x4*)(hout + off + i) = y;
    *(u16x4*)(bout_ + off + i) = pb;
  }
}

// ---------------------------------------------------------------------------
// head: out[b][o] = h[b, T-1, :] . Wout[:, o] + bout[o]
// ---------------------------------------------------------------------------
__global__ __launch_bounds__(256) void final_kernel(
    const float* __restrict__ h, const float* __restrict__ Wout,
    const float* __restrict__ bout, float* __restrict__ out)
{
  const int b = blockIdx.x, tid = threadIdx.x;
  __shared__ float row[2048];
  __shared__ float part[256];
  const float* hr = h + ((size_t)b * 64 + 63) * 2048;
  for (int i = tid; i < 2048; i += 256) row[i] = hr[i];
  __syncthreads();
  const int o = tid & 15, ch = tid >> 4;
  float s = 0.f;
  if (o < 10) {
    const int i0 = ch * 128;
    for (int i = i0; i < i0 + 128; i++) s = fmaf(row[i], Wout[(size_t)i * 10 + o], s);
  }
  part[tid] = s;
  __syncthreads();
  if (tid < 10) {
    float t = bout[tid];
    for (int c2 = 0; c2 < 16; c2++) t += part[c2 * 16 + tid];
    out[(size_t)b * 10 + tid] = t;
  }
}

// ---------------------------------------------------------------------------
extern "C" void kernel_launch(void* const* d_in, const int* in_sizes, int n_in,
                              void* d_out, int out_size, void* d_ws, size_t ws_size,
                              hipStream_t stream)
{
  const float* X        = (const float*)d_in[0];
  const float* V_Adap   = (const float*)d_in[1];
  const float* Wl       = (const float*)d_in[2];
  const float* bl       = (const float*)d_in[3];
  const float* Wr       = (const float*)d_in[4];
  const float* br       = (const float*)d_in[5];
  const float* att      = (const float*)d_in[6];
  const float* gat_bias = (const float*)d_in[7];
  const float* Wfc      = (const float*)d_in[8];
  const float* bfc      = (const float*)d_in[9];
  const float* Wq       = (const float*)d_in[10];
  const float* bq       = (const float*)d_in[11];
  const float* Wk       = (const float*)d_in[12];
  const float* bk       = (const float*)d_in[13];
  const float* Wv       = (const float*)d_in[14];
  const float* bv       = (const float*)d_in[15];
  const float* Wo       = (const float*)d_in[16];
  const float* bo       = (const float*)d_in[17];
  const float* ln1_g    = (const float*)d_in[18];
  const float* ln1_b    = (const float*)d_in[19];
  const float* W1       = (const float*)d_in[20];
  const float* b1       = (const float*)d_in[21];
  const float* W2       = (const float*)d_in[22];
  const float* b2       = (const float*)d_in[23];
  const float* ln2_g    = (const float*)d_in[24];
  const float* ln2_b    = (const float*)d_in[25];
  const float* WoutP    = (const float*)d_in[26];
  const float* boutP    = (const float*)d_in[27];
  const int*   class_idx = (const int*)d_in[28];

  char* ws = (char*)d_ws;
  const size_t MB = (size_t)1 << 20;
  float* h_f32 = (float*)(ws);               // 16 MB  (B*T, D) fp32
  u16*   h_b16 = (u16*)(ws + 16 * MB);       //  8 MB
  u16*   Qb    = (u16*)(ws + 24 * MB);       //  8 MB
  u16*   Kb    = (u16*)(ws + 32 * MB);       //  8 MB
  u16*   Vb    = (u16*)(ws + 40 * MB);       //  8 MB
  u16*   AOb   = (u16*)(ws + 48 * MB);       //  8 MB
  float* tmp   = (float*)(ws + 56 * MB);     // 16 MB  (proj / ff2) fp32
  u16*   ff1b  = (u16*)(ws + 72 * MB);       //  8 MB
  u16*   Wt0   = (u16*)(ws + 80 * MB);       //  8 MB transposed bf16 weights
  u16*   Wt1   = (u16*)(ws + 88 * MB);       //  8 MB
  u16*   Wt2   = (u16*)(ws + 96 * MB);       //  8 MB   (total 104 MB)

  // 1. GAT over all (b,t) graphs -> h (fp32 + bf16)
  gat_kernel<<<2048, 1024, 0, stream>>>(X, V_Adap, class_idx, Wl, bl, Wr, br,
                                        att, gat_bias, Wfc, bfc, h_f32, h_b16);

  const size_t DD = 2048ull * 2048ull;
  for (int l = 0; l < 2; l++) {
    const size_t wofs = (size_t)l * DD;
    const size_t bofs = (size_t)l * 2048;

    // QKV (batched z=3, 768 blocks, all co-resident at 48KB LDS)
    transpose_cast<<<dim3(32, 32, 3), 256, 0, stream>>>(
        TransArgs{Wq + wofs, Wk + wofs, Wv + wofs, Wt0, Wt1, Wt2});
    gemm_bt<1><<<dim3(16, 16, 3), 256, 0, stream>>>(
        GemmArgs{h_b16, Wt0, Wt1, Wt2, bq + bofs, bk + bofs, bv + bofs,
                 Qb, Kb, Vb, 2048, 2048});

    attn_kernel<<<dim3(16, 32), 256, 0, stream>>>(Qb, Kb, Vb, AOb);

    // o / W1 / W2 transposed together (Wt0..2 free once QKV gemm is done)
    transpose_cast<<<dim3(32, 32, 3), 256, 0, stream>>>(
        TransArgs{Wo + wofs, W1 + wofs, W2 + wofs, Wt0, Wt1, Wt2});

    // out-proj (128x64 tiles, 512 blocks)
    gemm_bt64<0><<<dim3(32, 16), 256, 0, stream>>>(
        GemmArgs{AOb, Wt0, nullptr, nullptr, bo + bofs, nullptr, nullptr,
                 tmp, nullptr, nullptr, 2048, 2048});
    ln_kernel<<<2048, 256, 0, stream>>>(h_f32, tmp, ln1_g + bofs, ln1_b + bofs,
                                        h_f32, h_b16);

    // FF1 (relu, bf16 out)
    gemm_bt64<2><<<dim3(32, 16), 256, 0, stream>>>(
        GemmArgs{h_b16, Wt1, nullptr, nullptr, b1 + bofs, nullptr, nullptr,
                 ff1b, nullptr, nullptr, 2048, 2048});

    // FF2
    gemm_bt64<0><<<dim3(32, 16), 256, 0, stream>>>(
        GemmArgs{ff1b, Wt2, nullptr, nullptr, b2 + bofs, nullptr, nullptr,
                 tmp, nullptr, nullptr, 2048, 2048});
    ln_kernel<<<2048, 256, 0, stream>>>(h_f32, tmp, ln2_g + bofs, ln2_b + bofs,
                                        h_f32, h_b16);
  }

  final_kernel<<<32, 256, 0, stream>>>(h_f32, WoutP, boutP, (float*)d_out);
}

// Round 5
// 873.000 us; speedup vs baseline: 1.1070x; 1.0016x over previous
//
#include <hip/hip_runtime.h>
#include <cstdint>
#include <cstddef>

// ---------------------------------------------------------------------------
// FullyDynamicSTGNN: GAT(128 nodes, T=64, B=32) -> 2-layer Transformer(d=2048)
// -> linear head.  Heavy GEMMs in bf16 MFMA (16x16x32), everything else fp32.
// R8: (1) split-K x2 GEMM for out-proj/FF2 (4 blocks/CU), combine fused into
//     a 2-delta ln (free);  (2) XCD 2D-chunk swizzle on all GEMM grids;
//     (3) attn QK^T via MFMA (bf16 LDS staging, fp32 acc - no new rounding);
//     (4) GAT stage 4 deleted (exp + row-partials fused into stage 3).
// ---------------------------------------------------------------------------

typedef unsigned short u16;
typedef __bf16 bf16x8 __attribute__((ext_vector_type(8)));
typedef float f32x4 __attribute__((ext_vector_type(4)));
typedef float f32x2 __attribute__((ext_vector_type(2)));
typedef unsigned int u32x4 __attribute__((ext_vector_type(4)));
typedef float f32x4v __attribute__((ext_vector_type(4)));
typedef unsigned short u16x4 __attribute__((ext_vector_type(4)));

__device__ __forceinline__ u16 f2b(float f) {
  union { float f; unsigned u; } x; x.f = f;
  unsigned r = x.u + 0x7fffu + ((x.u >> 16) & 1u);   // RNE
  return (u16)(r >> 16);
}
__device__ __forceinline__ float b2f(u16 s) {
  union { unsigned u; float f; } x; x.u = ((unsigned)s) << 16;
  return x.f;
}
__device__ __forceinline__ float b2f_lo(unsigned q) {
  union { unsigned u; float f; } x; x.u = q << 16;
  return x.f;
}
__device__ __forceinline__ float b2f_hi(unsigned q) {
  union { unsigned u; float f; } x; x.u = q & 0xffff0000u;
  return x.f;
}

// async global->LDS, 16B per lane; lds dest must be wave-uniform base (+lane*16)
__device__ __forceinline__ void gload_lds16(const void* g, void* l) {
  __builtin_amdgcn_global_load_lds(
      (const __attribute__((address_space(1))) unsigned int*)g,
      (__attribute__((address_space(3))) unsigned int*)l, 16, 0, 0);
}

// ---------------------------------------------------------------------------
// GAT kernel: one 1024-thread block per (b,t) graph.
// R8: stage 4 removed - exp + per-wave row partials computed in stage 3.
// ---------------------------------------------------------------------------
__global__ __launch_bounds__(1024) void gat_kernel(
    const float* __restrict__ X, const float* __restrict__ V_Adap,
    const int* __restrict__ class_idx,
    const float* __restrict__ Wl, const float* __restrict__ bl,
    const float* __restrict__ Wr, const float* __restrict__ br,
    const float* __restrict__ att, const float* __restrict__ gat_bias,
    const float* __restrict__ Wfc, const float* __restrict__ bfc,
    float* __restrict__ h_f32, u16* __restrict__ h_b16)
{
  const int bt = blockIdx.x;
  const int tid = threadIdx.x;

  __shared__ __align__(16) float xlT[64 * 132];     // 33792
  __shared__ __align__(16) float xrT[64 * 132];     // 33792
  __shared__ __align__(16) u16   xlTb[64 * 136];    // 17408
  __shared__ __align__(16) u16   esbT[128 * 136];   // 34816
  __shared__ __align__(16) u16   aggb[128 * 72];    // 18432 (X scratch / p-partials)
  __shared__ __align__(16) float WlT[64 * 20];      // 5120  [h][f]
  __shared__ __align__(16) float WrT[64 * 20];      // 5120
  __shared__ __align__(16) float WfcT[16 * 66];     // 4224  [s][h]
  __shared__ float atts[64], bls[64], brs[64], gbias[64], bfcs[16];
  __shared__ float cls[128], crs[128], inv_s[128];
  __shared__ float red[8 * 128];                    // 4096

  float* scratchX = (float*)aggb;   // 8KB of 18KB; aggb unused until stage 5
  float* red2 = (float*)aggb;       // 16x128 f32 p-partials (stage 3 use)

  // --- stage 0: load weights + stage X row-block into LDS ---
  {
    const int h = tid >> 4, f = tid & 15;
    WlT[h * 20 + f] = Wl[f * 64 + h];
    WrT[h * 20 + f] = Wr[f * 64 + h];
    WfcT[f * 66 + h] = Wfc[h * 16 + f];    // f plays 's' here
  }
  if (tid < 64) { atts[tid] = att[tid]; bls[tid] = bl[tid]; brs[tid] = br[tid]; gbias[tid] = gat_bias[tid]; }
  if (tid < 16) bfcs[tid] = bfc[tid];
  if (tid < 512)
    ((f32x4*)scratchX)[tid] = ((const f32x4*)(X + (size_t)bt * 2048))[tid];
  const int cidx = *class_idx;
  __syncthreads();

  // --- stage 1: xl = x@Wl+bl, xr = x@Wr+br.  (h = lane, node-group = wave) ---
  {
    const int h = tid & 63, ng = tid >> 6;        // ng == wave id (uniform)
    f32x4 wl4[4], wr4[4];
    #pragma unroll
    for (int f4 = 0; f4 < 4; f4++) {
      wl4[f4] = *(const f32x4*)&WlT[h * 20 + f4 * 4];
      wr4[f4] = *(const f32x4*)&WrT[h * 20 + f4 * 4];
    }
    const float blh = bls[h], brh = brs[h];
    float al8[8], ar8[8];
    #pragma unroll
    for (int t = 0; t < 8; t++) {
      const int n = ng * 8 + t;
      float al = blh, ar = brh;
      #pragma unroll
      for (int f4 = 0; f4 < 4; f4++) {
        const f32x4 xv = *(const f32x4*)&scratchX[n * 16 + f4 * 4];  // broadcast
        #pragma unroll
        for (int f = 0; f < 4; f++) {
          al = fmaf(xv[f], wl4[f4][f], al);
          ar = fmaf(xv[f], wr4[f4][f], ar);
        }
      }
      al8[t] = al; ar8[t] = ar;
    }
    *(f32x4*)&xlT[h * 132 + ng * 8]     = *(f32x4*)&al8[0];
    *(f32x4*)&xlT[h * 132 + ng * 8 + 4] = *(f32x4*)&al8[4];
    *(f32x4*)&xrT[h * 132 + ng * 8]     = *(f32x4*)&ar8[0];
    *(f32x4*)&xrT[h * 132 + ng * 8 + 4] = *(f32x4*)&ar8[4];
    u16 pb[8];
    #pragma unroll
    for (int t = 0; t < 8; t++) pb[t] = f2b(al8[t]);
    *(u16x4*)&xlTb[h * 136 + ng * 8]     = *(u16x4*)&pb[0];
    *(u16x4*)&xlTb[h * 136 + ng * 8 + 4] = *(u16x4*)&pb[4];
  }
  __syncthreads();

  // --- stage 2: cl[n] = att.xl[n], cr[n] = att.xr[n] (1024-thread partials) ---
  {
    const int n = tid & 127, g = tid >> 7;        // g 0..7
    const float* srcT = (g < 4) ? xlT : xrT;
    const int h0 = (g & 3) * 16;
    float s = 0.f;
    #pragma unroll
    for (int hh = 0; hh < 16; hh++)
      s = fmaf(atts[h0 + hh], srcT[(h0 + hh) * 132 + n], s);
    red[g * 128 + n] = s;
  }
  __syncthreads();
  if (tid < 256) {
    const int n = tid & 127;
    const int base = (tid < 128) ? 0 : 4;
    const float s = ((red[base * 128 + n] + red[(base + 1) * 128 + n])
                   + red[(base + 2) * 128 + n]) + red[(base + 3) * 128 + n];
    if (tid < 128) cls[n] = s; else crs[n] = s;
  }
  __syncthreads();

  // --- stage 3: e[i][j] -> p = exp(e) (bf16) -> esbT[j][i]; per-wave row
  //     partial sums -> red2[w][j].  8x2 tile, i0 wave-uniform. ---
  {
    const int w = tid >> 6;
    const int i0 = w * 8;                 // wave-uniform, 0..120
    const int j0 = (tid & 63) * 2;        // 0..126
    float acc[8][2] = {};
    #pragma unroll 8
    for (int h = 0; h < 64; h++) {
      const float ah = att[h];            // uniform -> s_load (SGPR)
      const f32x4 xa0 = *(const f32x4*)&xlT[h * 132 + i0];       // broadcast
      const f32x4 xa1 = *(const f32x4*)&xlT[h * 132 + i0 + 4];   // broadcast
      const f32x2 xb  = *(const f32x2*)&xrT[h * 132 + j0];
      #pragma unroll
      for (int a = 0; a < 4; a++) {
        acc[a][0]     = fmaf(ah, __builtin_fabsf(xa0[a] + xb[0]), acc[a][0]);
        acc[a][1]     = fmaf(ah, __builtin_fabsf(xa0[a] + xb[1]), acc[a][1]);
        acc[4 + a][0] = fmaf(ah, __builtin_fabsf(xa1[a] + xb[0]), acc[4 + a][0]);
        acc[4 + a][1] = fmaf(ah, __builtin_fabsf(xa1[a] + xb[1]), acc[4 + a][1]);
      }
    }
    const float* Vc = V_Adap + (size_t)cidx * 16384;
    float vm[8][2];
    #pragma unroll
    for (int a = 0; a < 8; a++) {
      const f32x2 vc = *(const f32x2*)&Vc[(size_t)(i0 + a) * 128 + j0];
      vm[a][0] = vc[0]; vm[a][1] = vc[1];
    }
    const f32x4 cl0 = *(const f32x4*)&cls[i0];
    const f32x4 cl1 = *(const f32x4*)&cls[i0 + 4];
    float cli[8] = {cl0[0], cl0[1], cl0[2], cl0[3], cl1[0], cl1[1], cl1[2], cl1[3]};
    float psum[2];
    #pragma unroll
    for (int b = 0; b < 2; b++) {
      const int j = j0 + b;
      const float ej = 0.6f * crs[j];
      u16 pk[8];
      float ps = 0.f;
      #pragma unroll
      for (int a = 0; a < 8; a++) {
        const int i = i0 + a;
        const float e = ej + 0.6f * cli[a] + 0.4f * acc[a][b];
        // sigmoid(v)/128 > 0.004  <=>  v > ln(0.512/0.488)
        const bool m = (vm[a][b] > 0.04800922f) || (i == j);
        const float p = m ? __expf(e) : 0.f;
        ps += p;
        pk[a] = f2b(p);
      }
      psum[b] = ps;
      *(u16x4*)&esbT[j * 136 + i0]     = *(u16x4*)&pk[0];
      *(u16x4*)&esbT[j * 136 + i0 + 4] = *(u16x4*)&pk[4];
    }
    *(f32x2*)&red2[w * 128 + j0] = *(f32x2*)&psum[0];
  }
  __syncthreads();
  if (tid < 128) {
    float s = 0.f;
    #pragma unroll
    for (int c = 0; c < 16; c++) s += red2[c * 128 + tid];
    inv_s[tid] = 1.f / s;
  }
  __syncthreads();

  // --- stage 5: agg[j][h] = (1/s_j) sum_i p^T[j][i] xl[i][h]  via MFMA ---
  {
    const int w = tid >> 6, lane = tid & 63;
    const int lq = lane >> 4, lr = lane & 15;
    const int jt = w >> 1, ht0 = (w & 1) * 2;
    f32x4 acc2[2] = {};
    #pragma unroll
    for (int ks = 0; ks < 4; ks++) {
      const bf16x8 af = __builtin_bit_cast(bf16x8,
          *(const u32x4*)&esbT[(jt * 16 + lr) * 136 + ks * 32 + lq * 8]);
      #pragma unroll
      for (int t = 0; t < 2; t++) {
        const bf16x8 bfb = __builtin_bit_cast(bf16x8,
            *(const u32x4*)&xlTb[((ht0 + t) * 16 + lr) * 136 + ks * 32 + lq * 8]);
        acc2[t] = __builtin_amdgcn_mfma_f32_16x16x32_bf16(af, bfb, acc2[t], 0, 0, 0);
      }
    }
    #pragma unroll
    for (int t = 0; t < 2; t++) {
      const int h = (ht0 + t) * 16 + lr;
      const float gb = gbias[h];
      #pragma unroll
      for (int r = 0; r < 4; r++) {
        const int j = jt * 16 + lq * 4 + r;
        aggb[j * 72 + h] = f2b(acc2[t][r] * inv_s[j] + gb);
      }
    }
  }
  __syncthreads();

  // --- stage 6: out = agg @ Wfc + bfc -> h (fp32 + bf16) ---
  {
    const int j = tid >> 3, s0 = (tid & 7) * 2;
    float o0 = bfcs[s0], o1 = bfcs[s0 + 1];
    #pragma unroll
    for (int h8 = 0; h8 < 8; h8++) {
      u32x4 q = *(const u32x4*)&aggb[j * 72 + h8 * 8];
      #pragma unroll
      for (int w2 = 0; w2 < 4; w2++) {
        const int h = h8 * 8 + w2 * 2;
        const float a0 = b2f_lo(q[w2]);
        const float a1 = b2f_hi(q[w2]);
        o0 = fmaf(a0, WfcT[s0 * 66 + h], o0);
        o1 = fmaf(a0, WfcT[(s0 + 1) * 66 + h], o1);
        o0 = fmaf(a1, WfcT[s0 * 66 + h + 1], o0);
        o1 = fmaf(a1, WfcT[(s0 + 1) * 66 + h + 1], o1);
      }
    }
    const size_t off = (size_t)bt * 2048 + j * 16 + s0;
    h_f32[off] = o0; h_f32[off + 1] = o1;
    h_b16[off] = f2b(o0); h_b16[off + 1] = f2b(o1);
  }
}

// ---------------------------------------------------------------------------
// transpose + cast: src (2048 x 2048) fp32 row-major -> dst bf16 (dst[n][k] =
// src[k][n]).  Up to 3 matrices via blockIdx.z.
// ---------------------------------------------------------------------------
struct TransArgs {
  const float* s0; const float* s1; const float* s2;
  u16* d0; u16* d1; u16* d2;
};

__global__ __launch_bounds__(256) void transpose_cast(TransArgs p)
{
  const float* src = (blockIdx.z == 0) ? p.s0 : (blockIdx.z == 1) ? p.s1 : p.s2;
  u16* dst = (blockIdx.z == 0) ? p.d0 : (blockIdx.z == 1) ? p.d1 : p.d2;
  __shared__ u16 tile[64][66];
  const int k0 = blockIdx.y * 64, n0 = blockIdx.x * 64;
  const int tid = threadIdx.x;
  const int c = tid & 63, rb = tid >> 6;
  #pragma unroll
  for (int r = 0; r < 16; r++) {
    const int k = rb + r * 4;
    tile[k][c] = f2b(src[(size_t)(k0 + k) * 2048 + n0 + c]);
  }
  __syncthreads();
  #pragma unroll
  for (int r = 0; r < 16; r++) {
    const int n = rb + r * 4;
    dst[(size_t)(n0 + n) * 2048 + k0 + c] = tile[c][n];
  }
}

// ---------------------------------------------------------------------------
// bf16 MFMA GEMM: C[m][n] = sum_k A[m][k] * Bt[n][k] + bias[n]
// 3-buffer ring, counted vmcnt, raw barriers, setprio around compute.
// XCD 2D-chunk swizzle on block coords (per-XCD L2 locality).
// ---------------------------------------------------------------------------
struct GemmArgs {
  const u16* A;
  const u16* Bt0; const u16* Bt1; const u16* Bt2;
  const float* b0; const float* b1; const float* b2;
  void* C0; void* C1; void* C2;
  int N; int K;
};

// 128x128 tile, BK=32, 3-buf (48KB LDS -> 3 blocks/CU, 768-block grid resident).
// L = 4 gload_lds per stage per wave -> vmcnt 8/4/0.
template <int MODE>
__global__ __launch_bounds__(256) void gemm_bt(GemmArgs g)
{
  const int z = blockIdx.z;
  const u16* Bt = (z == 0) ? g.Bt0 : (z == 1) ? g.Bt1 : g.Bt2;
  const float* bias = (z == 0) ? g.b0 : (z == 1) ? g.b1 : g.b2;
  void* C = (z == 0) ? g.C0 : (z == 1) ? g.C1 : g.C2;
  const int N = g.N, K = g.K;
  // XCD swizzle: 16x16 tile grid -> XCD c gets a 4x8 chunk (c = x&7 = lin%8)
  const int lin = blockIdx.y * 16 + blockIdx.x;
  const int xc = lin & 7, xt = lin >> 3;           // xt 0..31
  const int wx = (xc & 3) * 4 + (xt & 3);
  const int wy = (xc >> 2) * 8 + (xt >> 2);
  const int m0 = wy * 128, n0 = wx * 128;

  __shared__ __align__(16) u16 As[3][128 * 32];   // 24KB
  __shared__ __align__(16) u16 Bs[3][128 * 32];   // 24KB

  const int tid = threadIdx.x;
  const int lane = tid & 63, w = tid >> 6;
  const int srow = w * 16 + (lane >> 2);
  const int scol = ((lane & 3) ^ ((lane >> 2) & 3)) * 8;
  const u16* gA = g.A + (size_t)(m0 + srow) * K + scol;
  const u16* gB = Bt + (size_t)(n0 + srow) * K + scol;
  const int lbase = (w * 16) * 32;

  const int wm = (w >> 1) * 64, wn = (w & 1) * 64;
  const int lq = lane >> 4, lr = lane & 15;
  const int csw = (lr & 3) << 3;                  // read-side XOR (elements)

  f32x4 acc[4][4] = {};
  const int NT = K >> 5;

  auto stage = [&](int buf, int kt) {
    const int kk = kt << 5;
    #pragma unroll
    for (int c = 0; c < 2; c++) {
      gload_lds16(gA + (size_t)(c * 64) * K + kk, &As[buf][lbase + c * 64 * 32]);
      gload_lds16(gB + (size_t)(c * 64) * K + kk, &Bs[buf][lbase + c * 64 * 32]);
    }
  };
  auto compute = [&](int buf) {
    bf16x8 af[4], bfr[4];
    #pragma unroll
    for (int i = 0; i < 4; i++) {
      af[i] = __builtin_bit_cast(bf16x8,
          *(const u32x4*)&As[buf][(wm + i * 16 + lr) * 32 + ((lq * 8) ^ csw)]);
      bfr[i] = __builtin_bit_cast(bf16x8,
          *(const u32x4*)&Bs[buf][(wn + i * 16 + lr) * 32 + ((lq * 8) ^ csw)]);
    }
    #pragma unroll
    for (int mi = 0; mi < 4; mi++)
      #pragma unroll
      for (int ni = 0; ni < 4; ni++)
        acc[mi][ni] = __builtin_amdgcn_mfma_f32_16x16x32_bf16(af[mi], bfr[ni], acc[mi][ni], 0, 0, 0);
  };

  stage(0, 0);
  stage(1, 1);
  int cA = 0;                          // buffer holding tile kt
  for (int kt = 0; kt < NT; ++kt) {
    if (kt + 2 < NT) {
      int b2 = cA + 2; if (b2 >= 3) b2 -= 3;
      stage(b2, kt + 2);
      asm volatile("s_waitcnt vmcnt(8)" ::: "memory");
    } else if (kt + 1 < NT) {
      asm volatile("s_waitcnt vmcnt(4)" ::: "memory");
    } else {
      asm volatile("s_waitcnt vmcnt(0)" ::: "memory");
    }
    __builtin_amdgcn_s_barrier();
    asm volatile("" ::: "memory");
    __builtin_amdgcn_s_setprio(1);
    compute(cA);
    __builtin_amdgcn_s_setprio(0);
    asm volatile("" ::: "memory");
    __builtin_amdgcn_s_barrier();
    asm volatile("" ::: "memory");
    if (++cA == 3) cA = 0;
  }

  #pragma unroll
  for (int ni = 0; ni < 4; ni++) {
    const int col = n0 + wn + ni * 16 + lr;
    const float bv = bias[col];
    #pragma unroll
    for (int mi = 0; mi < 4; mi++) {
      #pragma unroll
      for (int r = 0; r < 4; r++) {
        const int row = m0 + wm + mi * 16 + lq * 4 + r;
        float v = acc[mi][ni][r] + bv;
        if (MODE == 0) {
          ((float*)C)[(size_t)row * N + col] = v;
        } else {
          if (MODE == 2) v = fmaxf(v, 0.f);
          ((u16*)C)[(size_t)row * N + col] = f2b(v);
        }
      }
    }
  }
}

// 128(M) x 64(N) tile, BK=64, 3-buf (72KB LDS, 2 blocks/CU).  Full-K (FF1).
// L = 6 -> vmcnt 12/6/0.
template <int MODE>
__global__ __launch_bounds__(256) void gemm_bt64(GemmArgs g)
{
  const u16* Bt = g.Bt0;
  const float* bias = g.b0;
  void* C = g.C0;
  const int N = g.N, K = g.K;
  // XCD swizzle: 32x16 grid -> XCD c gets an 8x8 chunk (c = x&7 = lin%8)
  const int lin = blockIdx.y * 32 + blockIdx.x;
  const int xc = lin & 7, xt = lin >> 3;           // xt 0..63
  const int wx = (xc & 3) * 8 + (xt & 7);
  const int wy = (xc >> 2) * 8 + (xt >> 3);
  const int m0 = wy * 128, n0 = wx * 64;

  __shared__ __align__(16) u16 As[3][128 * 64];   // 48KB
  __shared__ __align__(16) u16 Bs[3][64 * 64];    // 24KB

  const int tid = threadIdx.x;
  const int lane = tid & 63, w = tid >> 6;
  const int srow = w * 8 + (lane >> 3);
  const int scol = ((lane & 7) ^ (lane >> 3)) * 8;   // pre-swizzled global col
  const u16* gA = g.A + (size_t)(m0 + srow) * K + scol;
  const u16* gB = Bt + (size_t)(n0 + srow) * K + scol;
  const int lbase = (w * 8) * 64;

  const int wm = w * 32;
  const int lq = lane >> 4, lr = lane & 15;
  const int csw = (lr & 7) << 3;                  // read-side XOR (elements)

  f32x4 acc[2][4] = {};
  const int NT = K >> 6;

  auto stage = [&](int buf, int kt) {
    const int kk = kt << 6;
    #pragma unroll
    for (int c = 0; c < 4; c++)
      gload_lds16(gA + (size_t)(c * 32) * K + kk, &As[buf][lbase + c * 32 * 64]);
    #pragma unroll
    for (int c = 0; c < 2; c++)
      gload_lds16(gB + (size_t)(c * 32) * K + kk, &Bs[buf][lbase + c * 32 * 64]);
  };
  auto compute = [&](int buf) {
    #pragma unroll
    for (int ks = 0; ks < 2; ks++) {
      bf16x8 af[2], bfr[4];
      #pragma unroll
      for (int i = 0; i < 2; i++)
        af[i] = __builtin_bit_cast(bf16x8,
            *(const u32x4*)&As[buf][(wm + i * 16 + lr) * 64 + ((ks * 32 + lq * 8) ^ csw)]);
      #pragma unroll
      for (int i = 0; i < 4; i++)
        bfr[i] = __builtin_bit_cast(bf16x8,
            *(const u32x4*)&Bs[buf][(i * 16 + lr) * 64 + ((ks * 32 + lq * 8) ^ csw)]);
      #pragma unroll
      for (int mi = 0; mi < 2; mi++)
        #pragma unroll
        for (int ni = 0; ni < 4; ni++)
          acc[mi][ni] = __builtin_amdgcn_mfma_f32_16x16x32_bf16(af[mi], bfr[ni], acc[mi][ni], 0, 0, 0);
    }
  };

  stage(0, 0);
  stage(1, 1);
  int cA = 0;
  for (int kt = 0; kt < NT; ++kt) {
    if (kt + 2 < NT) {
      int b2 = cA + 2; if (b2 >= 3) b2 -= 3;
      stage(b2, kt + 2);
      asm volatile("s_waitcnt vmcnt(12)" ::: "memory");
    } else if (kt + 1 < NT) {
      asm volatile("s_waitcnt vmcnt(6)" ::: "memory");
    } else {
      asm volatile("s_waitcnt vmcnt(0)" ::: "memory");
    }
    __builtin_amdgcn_s_barrier();
    asm volatile("" ::: "memory");
    __builtin_amdgcn_s_setprio(1);
    compute(cA);
    __builtin_amdgcn_s_setprio(0);
    asm volatile("" ::: "memory");
    __builtin_amdgcn_s_barrier();
    asm volatile("" ::: "memory");
    if (++cA == 3) cA = 0;
  }

  #pragma unroll
  for (int ni = 0; ni < 4; ni++) {
    const int col = n0 + ni * 16 + lr;
    const float bv = bias[col];
    #pragma unroll
    for (int mi = 0; mi < 2; mi++) {
      #pragma unroll
      for (int r = 0; r < 4; r++) {
        const int row = m0 + wm + mi * 16 + lq * 4 + r;
        float v = acc[mi][ni][r] + bv;
        if (MODE == 0) {
          ((float*)C)[(size_t)row * N + col] = v;
        } else {
          if (MODE == 2) v = fmaxf(v, 0.f);
          ((u16*)C)[(size_t)row * N + col] = f2b(v);
        }
      }
    }
  }
}

// Split-K GEMM: 128(M) x 64(N) tile, BK=32, 3-buf (36KB LDS -> 4 blocks/CU),
// grid (32,16,2): z = K-half.  fp32 partials C0/C1; bias folded into z=0.
// L = 3 gload per stage per wave -> vmcnt 6/3/0.
__global__ __launch_bounds__(256) void gemm_bt64sk(
    const u16* __restrict__ A, const u16* __restrict__ Bt,
    const float* __restrict__ bias, float* __restrict__ C0,
    float* __restrict__ C1, int N, int K)
{
  const int z = blockIdx.z;
  float* C = z ? C1 : C0;
  const int khalf = K >> 1;
  // XCD swizzle within the 512-block slice (slice size % 8 == 0).
  const int lin = blockIdx.y * 32 + blockIdx.x;
  const int xc = lin & 7, xt = lin >> 3;           // xt 0..63
  const int wx = (xc & 3) * 8 + (xt & 7);
  const int wy = (xc >> 2) * 8 + (xt >> 3);
  const int m0 = wy * 128, n0 = wx * 64;

  __shared__ __align__(16) u16 As[3][128 * 32];   // 24KB
  __shared__ __align__(16) u16 Bs[3][64 * 32];    // 12KB

  const int tid = threadIdx.x;
  const int lane = tid & 63, w = tid >> 6;
  const int srow = w * 16 + (lane >> 2);
  const int scol = ((lane & 3) ^ ((lane >> 2) & 3)) * 8;
  const u16* gA = A + (size_t)(m0 + srow) * K + (size_t)z * khalf + scol;
  const u16* gB = Bt + (size_t)(n0 + srow) * K + (size_t)z * khalf + scol;
  const int lbaseA = (w * 16) * 32;
  const int lbaseB = (w * 16) * 32;

  const int wm = w * 32;
  const int lq = lane >> 4, lr = lane & 15;
  const int csw = (lr & 3) << 3;                  // read-side XOR (elements)

  f32x4 acc[2][4] = {};
  const int NT = khalf >> 5;                      // 32

  auto stage = [&](int buf, int kt) {
    const int kk = kt << 5;
    gload_lds16(gA + kk, &As[buf][lbaseA]);
    gload_lds16(gA + (size_t)64 * K + kk, &As[buf][lbaseA + 64 * 32]);
    gload_lds16(gB + kk, &Bs[buf][lbaseB]);
  };
  auto compute = [&](int buf) {
    bf16x8 af[2], bfr[4];
    #pragma unroll
    for (int i = 0; i < 2; i++)
      af[i] = __builtin_bit_cast(bf16x8,
          *(const u32x4*)&As[buf][(wm + i * 16 + lr) * 32 + ((lq * 8) ^ csw)]);
    #pragma unroll
    for (int i = 0; i < 4; i++)
      bfr[i] = __builtin_bit_cast(bf16x8,
          *(const u32x4*)&Bs[buf][(i * 16 + lr) * 32 + ((lq * 8) ^ csw)]);
    #pragma unroll
    for (int mi = 0; mi < 2; mi++)
      #pragma unroll
      for (int ni = 0; ni < 4; ni++)
        acc[mi][ni] = __builtin_amdgcn_mfma_f32_16x16x32_bf16(af[mi], bfr[ni], acc[mi][ni], 0, 0, 0);
  };

  stage(0, 0);
  stage(1, 1);
  int cA = 0;
  for (int kt = 0; kt < NT; ++kt) {
    if (kt + 2 < NT) {
      int b2 = cA + 2; if (b2 >= 3) b2 -= 3;
      stage(b2, kt + 2);
      asm volatile("s_waitcnt vmcnt(6)" ::: "memory");
    } else if (kt + 1 < NT) {
      asm volatile("s_waitcnt vmcnt(3)" ::: "memory");
    } else {
      asm volatile("s_waitcnt vmcnt(0)" ::: "memory");
    }
    __builtin_amdgcn_s_barrier();
    asm volatile("" ::: "memory");
    __builtin_amdgcn_s_setprio(1);
    compute(cA);
    __builtin_amdgcn_s_setprio(0);
    asm volatile("" ::: "memory");
    __builtin_amdgcn_s_barrier();
    asm volatile("" ::: "memory");
    if (++cA == 3) cA = 0;
  }

  #pragma unroll
  for (int ni = 0; ni < 4; ni++) {
    const int col = n0 + ni * 16 + lr;
    const float bv = z ? 0.f : bias[col];
    #pragma unroll
    for (int mi = 0; mi < 2; mi++) {
      #pragma unroll
      for (int r = 0; r < 4; r++) {
        const int row = m0 + wm + mi * 16 + lq * 4 + r;
        C[(size_t)row * N + col] = acc[mi][ni][r] + bv;
      }
    }
  }
}

// ---------------------------------------------------------------------------
// attention: one block per (head, batch).  S=64, DH=128.
// R8: QK^T via MFMA (Q/K staged raw bf16, stride 136 -> conflict-free b128
// frags, fp32 accum == same math, reordered).  Softmax + PV unchanged (fp32).
// ---------------------------------------------------------------------------
__global__ __launch_bounds__(256) void attn_kernel(
    const u16* __restrict__ Qb, const u16* __restrict__ Kb,
    const u16* __restrict__ Vb, u16* __restrict__ AOb)
{
  const int head = blockIdx.x, b = blockIdx.y;
  const int tid = threadIdx.x;
  __shared__ __align__(16) u16   qs16[64 * 136];   // 17408
  __shared__ __align__(16) u16   ks16[64 * 136];   // 17408
  __shared__ __align__(16) float vs[64 * 128];     // 32768
  __shared__ __align__(16) float ss[64 * 65];      // 16640
  const size_t base = ((size_t)b * 64) * 2048 + (size_t)head * 128;

  for (int idx = tid; idx < 1024; idx += 256) {
    const int t_ = idx >> 4, d8 = (idx & 15) * 8;
    const size_t gp = base + (size_t)t_ * 2048 + d8;
    const u32x4 q = *(const u32x4*)(Qb + gp);
    const u32x4 k = *(const u32x4*)(Kb + gp);
    const u32x4 v = *(const u32x4*)(Vb + gp);
    *(u32x4*)&qs16[t_ * 136 + d8] = q;
    *(u32x4*)&ks16[t_ * 136 + d8] = k;
    f32x4 v0 = {b2f_lo(v[0]), b2f_hi(v[0]), b2f_lo(v[1]), b2f_hi(v[1])};
    f32x4 v1 = {b2f_lo(v[2]), b2f_hi(v[2]), b2f_lo(v[3]), b2f_hi(v[3])};
    *(f32x4*)&vs[t_ * 128 + d8] = v0; *(f32x4*)&vs[t_ * 128 + d8 + 4] = v1;
  }
  __syncthreads();

  // --- QK^T via MFMA: wave w owns S cols j in [w*16, w*16+16) ---
  {
    const int w = tid >> 6, lane = tid & 63;
    const int lq = lane >> 4, lr = lane & 15;
    f32x4 acc4[4] = {};
    #pragma unroll
    for (int ks = 0; ks < 4; ks++) {
      const bf16x8 kf = __builtin_bit_cast(bf16x8,
          *(const u32x4*)&ks16[(w * 16 + lr) * 136 + ks * 32 + lq * 8]);
      #pragma unroll
      for (int mi = 0; mi < 4; mi++) {
        const bf16x8 qf = __builtin_bit_cast(bf16x8,
            *(const u32x4*)&qs16[(mi * 16 + lr) * 136 + ks * 32 + lq * 8]);
        acc4[mi] = __builtin_amdgcn_mfma_f32_16x16x32_bf16(qf, kf, acc4[mi], 0, 0, 0);
      }
    }
    const float sc = 0.08838834764831845f;  // 1/sqrt(128)
    #pragma unroll
    for (int mi = 0; mi < 4; mi++)
      #pragma unroll
      for (int r = 0; r < 4; r++)
        ss[(mi * 16 + lq * 4 + r) * 65 + w * 16 + lr] = acc4[mi][r] * sc;
  }
  __syncthreads();

  {
    const int row = tid >> 2;
    float* rp = &ss[row * 65 + (tid & 3) * 16];
    float mx = -3e38f;
    #pragma unroll
    for (int j = 0; j < 16; j++) mx = fmaxf(mx, rp[j]);
    mx = fmaxf(mx, __shfl_xor(mx, 1, 64));
    mx = fmaxf(mx, __shfl_xor(mx, 2, 64));
    float s = 0.f;
    #pragma unroll
    for (int j = 0; j < 16; j++) { const float p = __expf(rp[j] - mx); rp[j] = p; s += p; }
    s += __shfl_xor(s, 1, 64);
    s += __shfl_xor(s, 2, 64);
    const float inv = 1.f / s;
    #pragma unroll
    for (int j = 0; j < 16; j++) rp[j] *= inv;
  }
  __syncthreads();

  {
    const int i0 = (tid >> 4) * 4, d0 = (tid & 15) * 8;
    float o[4][8] = {};
    for (int j = 0; j < 64; j++) {
      float pv[4];
      #pragma unroll
      for (int a = 0; a < 4; a++) pv[a] = ss[(i0 + a) * 65 + j];
      f32x4v v0 = *(const f32x4v*)&vs[j * 128 + d0];
      f32x4v v1 = *(const f32x4v*)&vs[j * 128 + d0 + 4];
      float vv[8] = {v0[0], v0[1], v0[2], v0[3], v1[0], v1[1], v1[2], v1[3]};
      #pragma unroll
      for (int a = 0; a < 4; a++)
        #pragma unroll
        for (int c = 0; c < 8; c++)
          o[a][c] = fmaf(pv[a], vv[c], o[a][c]);
    }
    #pragma unroll
    for (int a = 0; a < 4; a++)
      #pragma unroll
      for (int c = 0; c < 8; c++)
        AOb[base + (size_t)(i0 + a) * 2048 + d0 + c] = f2b(o[a][c]);
  }
}

// ---------------------------------------------------------------------------
// fused residual + layernorm: h = LN(hin + d0 + d1) ; writes fp32 + bf16
// (d0/d1 are the split-K GEMM partials; d0 carries the bias.)
// ---------------------------------------------------------------------------
__global__ __launch_bounds__(256) void ln_kernel(
    const float* __restrict__ hin, const float* __restrict__ d0,
    const float* __restrict__ d1,
    const float* __restrict__ gamma, const float* __restrict__ beta,
    float* __restrict__ hout, u16* __restrict__ bout_)
{
  const int token = blockIdx.x, tid = threadIdx.x;
  const size_t off = (size_t)token * 2048;
  __shared__ float red[8];
  f32x4 v[2];
  float s = 0.f;
  #pragma unroll
  for (int r = 0; r < 2; r++) {
    const int i = r * 1024 + tid * 4;
    const f32x4 a = *(const f32x4*)(hin + off + i);
    const f32x4 b0 = *(const f32x4*)(d0 + off + i);
    const f32x4 b1 = *(const f32x4*)(d1 + off + i);
    v[r] = a + b0 + b1;
    s += v[r][0] + v[r][1] + v[r][2] + v[r][3];
  }
  #pragma unroll
  for (int o = 32; o > 0; o >>= 1) s += __shfl_down(s, o, 64);
  if ((tid & 63) == 0) red[tid >> 6] = s;
  __syncthreads();
  const float mean = (red[0] + red[1] + red[2] + red[3]) * (1.f / 2048.f);
  float s2 = 0.f;
  #pragma unroll
  for (int r = 0; r < 2; r++)
    #pragma unroll
    for (int e = 0; e < 4; e++) { const float d = v[r][e] - mean; s2 = fmaf(d, d, s2); }
  #pragma unroll
  for (int o = 32; o > 0; o >>= 1) s2 += __shfl_down(s2, o, 64);
  if ((tid & 63) == 0) red[4 + (tid >> 6)] = s2;
  __syncthreads();
  const float var = (red[4] + red[5] + red[6] + red[7]) * (1.f / 2048.f);
  const float rstd = rsqrtf(var + 1e-5f);
  #pragma unroll
  for (int r = 0; r < 2; r++) {
    const int i = r * 1024 + tid * 4;
    const f32x4 gm = *(const f32x4*)(gamma + i);
    const f32x4 bt = *(const f32x4*)(beta + i);
    f32x4 y;
    u16x4 pb;
    #pragma unroll
    for (int e = 0; e < 4; e++) {
      y[e] = (v[r][e] - mean) * rstd * gm[e] + bt[e];
      pb[e] = f2b(y[e]);
    }
    *(f32x4*)(hout + off + i) = y;
    *(u16x4*)(bout_ + off + i) = pb;
  }
}

// ---------------------------------------------------------------------------
// head: out[b][o] = h[b, T-1, :] . Wout[:, o] + bout[o]
// ---------------------------------------------------------------------------
__global__ __launch_bounds__(256) void final_kernel(
    const float* __restrict__ h, const float* __restrict__ Wout,
    const float* __restrict__ bout, float* __restrict__ out)
{
  const int b = blockIdx.x, tid = threadIdx.x;
  __shared__ float row[2048];
  __shared__ float part[256];
  const float* hr = h + ((size_t)b * 64 + 63) * 2048;
  for (int i = tid; i < 2048; i += 256) row[i] = hr[i];
  __syncthreads();
  const int o = tid & 15, ch = tid >> 4;
  float s = 0.f;
  if (o < 10) {
    const int i0 = ch * 128;
    for (int i = i0; i < i0 + 128; i++) s = fmaf(row[i], Wout[(size_t)i * 10 + o], s);
  }
  part[tid] = s;
  __syncthreads();
  if (tid < 10) {
    float t = bout[tid];
    for (int c2 = 0; c2 < 16; c2++) t += part[c2 * 16 + tid];
    out[(size_t)b * 10 + tid] = t;
  }
}

// ---------------------------------------------------------------------------
extern "C" void kernel_launch(void* const* d_in, const int* in_sizes, int n_in,
                              void* d_out, int out_size, void* d_ws, size_t ws_size,
                              hipStream_t stream)
{
  const float* X        = (const float*)d_in[0];
  const float* V_Adap   = (const float*)d_in[1];
  const float* Wl       = (const float*)d_in[2];
  const float* bl       = (const float*)d_in[3];
  const float* Wr       = (const float*)d_in[4];
  const float* br       = (const float*)d_in[5];
  const float* att      = (const float*)d_in[6];
  const float* gat_bias = (const float*)d_in[7];
  const float* Wfc      = (const float*)d_in[8];
  const float* bfc      = (const float*)d_in[9];
  const float* Wq       = (const float*)d_in[10];
  const float* bq       = (const float*)d_in[11];
  const float* Wk       = (const float*)d_in[12];
  const float* bk       = (const float*)d_in[13];
  const float* Wv       = (const float*)d_in[14];
  const float* bv       = (const float*)d_in[15];
  const float* Wo       = (const float*)d_in[16];
  const float* bo       = (const float*)d_in[17];
  const float* ln1_g    = (const float*)d_in[18];
  const float* ln1_b    = (const float*)d_in[19];
  const float* W1       = (const float*)d_in[20];
  const float* b1       = (const float*)d_in[21];
  const float* W2       = (const float*)d_in[22];
  const float* b2       = (const float*)d_in[23];
  const float* ln2_g    = (const float*)d_in[24];
  const float* ln2_b    = (const float*)d_in[25];
  const float* WoutP    = (const float*)d_in[26];
  const float* boutP    = (const float*)d_in[27];
  const int*   class_idx = (const int*)d_in[28];

  char* ws = (char*)d_ws;
  const size_t MB = (size_t)1 << 20;
  float* h_f32 = (float*)(ws);               // 16 MB  (B*T, D) fp32
  u16*   h_b16 = (u16*)(ws + 16 * MB);       //  8 MB
  u16*   Qb    = (u16*)(ws + 24 * MB);       //  8 MB
  u16*   Kb    = (u16*)(ws + 32 * MB);       //  8 MB
  u16*   Vb    = (u16*)(ws + 40 * MB);       //  8 MB
  u16*   AOb   = (u16*)(ws + 48 * MB);       //  8 MB
  float* tmp   = (float*)(ws + 56 * MB);     // 16 MB  (split-K partial P1)
  u16*   ff1b  = (u16*)(ws + 72 * MB);       //  8 MB
  u16*   Wt0   = (u16*)(ws + 80 * MB);       //  8 MB transposed bf16 weights
  u16*   Wt1   = (u16*)(ws + 88 * MB);       //  8 MB
  u16*   Wt2   = (u16*)(ws + 96 * MB);       //  8 MB   (total 104 MB)
  // split-K partial P0 lives over Qb+Kb (dead once attn has run)
  float* P0 = (float*)(ws + 24 * MB);        // 16 MB
  float* P1 = tmp;                           // 16 MB

  // 1. GAT over all (b,t) graphs -> h (fp32 + bf16)
  gat_kernel<<<2048, 1024, 0, stream>>>(X, V_Adap, class_idx, Wl, bl, Wr, br,
                                        att, gat_bias, Wfc, bfc, h_f32, h_b16);

  const size_t DD = 2048ull * 2048ull;
  for (int l = 0; l < 2; l++) {
    const size_t wofs = (size_t)l * DD;
    const size_t bofs = (size_t)l * 2048;

    // QKV (batched z=3, 768 blocks, all co-resident at 48KB LDS)
    transpose_cast<<<dim3(32, 32, 3), 256, 0, stream>>>(
        TransArgs{Wq + wofs, Wk + wofs, Wv + wofs, Wt0, Wt1, Wt2});
    gemm_bt<1><<<dim3(16, 16, 3), 256, 0, stream>>>(
        GemmArgs{h_b16, Wt0, Wt1, Wt2, bq + bofs, bk + bofs, bv + bofs,
                 Qb, Kb, Vb, 2048, 2048});

    attn_kernel<<<dim3(16, 32), 256, 0, stream>>>(Qb, Kb, Vb, AOb);

    // o / W1 / W2 transposed together (Wt0..2 free once QKV gemm is done)
    transpose_cast<<<dim3(32, 32, 3), 256, 0, stream>>>(
        TransArgs{Wo + wofs, W1 + wofs, W2 + wofs, Wt0, Wt1, Wt2});

    // out-proj: split-K x2 (1024 blocks, 4/CU); combine fused into ln1
    gemm_bt64sk<<<dim3(32, 16, 2), 256, 0, stream>>>(
        AOb, Wt0, bo + bofs, P0, P1, 2048, 2048);
    ln_kernel<<<2048, 256, 0, stream>>>(h_f32, P0, P1, ln1_g + bofs, ln1_b + bofs,
                                        h_f32, h_b16);

    // FF1 (relu, bf16 out) - full K
    gemm_bt64<2><<<dim3(32, 16), 256, 0, stream>>>(
        GemmArgs{h_b16, Wt1, nullptr, nullptr, b1 + bofs, nullptr, nullptr,
                 ff1b, nullptr, nullptr, 2048, 2048});

    // FF2: split-K x2; combine fused into ln2
    gemm_bt64sk<<<dim3(32, 16, 2), 256, 0, stream>>>(
        ff1b, Wt2, b2 + bofs, P0, P1, 2048, 2048);
    ln_kernel<<<2048, 256, 0, stream>>>(h_f32, P0, P1, ln2_g + bofs, ln2_b + bofs,
                                        h_f32, h_b16);
  }

  final_kernel<<<32, 256, 0, stream>>>(h_f32, WoutP, boutP, (float*)d_out);
}